// Round 5
// baseline (584.654 us; speedup 1.0000x reference)
//
#include <hip/hip_runtime.h>
#include <math.h>

#define NN 4096
#define LN_EPS 1e-5f
#define EPS 1e-8f

typedef unsigned short ushortT;
typedef unsigned int uintT;
typedef __attribute__((ext_vector_type(8))) short short8;
typedef __attribute__((ext_vector_type(4))) float f32x4;
typedef __attribute__((ext_vector_type(4))) unsigned short us4;

// workspace offsets (in floats)
// ktF: bf16 A-frags  [b][c=64][frag=8][lane=64][j=8] = 16.78M ushorts (32 MB)
// vF : bf16 B-frags  same shape
// qF : bf16 B-frags  [b][kb=2][lane=64][j=8] = 65536 ushorts (128 KB)
#define OFF_KT    0L
#define OFF_V     16777216L
#define OFF_QT    33554432L
#define OFF_ACC   33587200L   // acc [b][k][d] f32          32768
#define OFF_COL   33619968L   // colsum [b][k] f32          512
#define OFF_SLOTS 33620480L   // slots [b][k][d] f32        32768
#define OFF_WIHT  33653248L   // w_ih^T [64][192]           12288
#define OFF_WHHT  33665536L   // w_hh^T [64][192]           12288
#define OFF_W1T   33677824L   // mlp_w1^T [64][128]         8192
#define OFF_W2T   33686016L   // mlp_w2^T [128][64]         8192
#define OFF_WQT   33694208L   // Wq^T [64][64]              4096
#define OFF_WKV   33698304L   // wpack bf16 MFMA B-frags    8192 ushorts (4096 f)
#define OFF_CNT   33702400L   // per-batch arrival counters 64 ints

__device__ __forceinline__ float wredsum(float v) {
#pragma unroll
  for (int off = 32; off > 0; off >>= 1) v += __shfl_xor(v, off);
  return v;
}

__device__ __forceinline__ ushortT f2bf(float f) {
  uintT b = __float_as_uint(f);
  b += 0x7fff + ((b >> 16) & 1);          // RNE
  return (ushortT)(b >> 16);
}

// ---------------------------------------------------------------------------
// K0: weight prep. wpack: B-frags for LN-projection GEMM.
__global__ __launch_bounds__(256) void k_prep(
    const float* __restrict__ w_ih, const float* __restrict__ w_hh,
    const float* __restrict__ w1, const float* __restrict__ w2,
    const float* __restrict__ Wq,
    const float* __restrict__ Wk, const float* __restrict__ Wv,
    float* __restrict__ wihT, float* __restrict__ whhT,
    float* __restrict__ w1T, float* __restrict__ w2T, float* __restrict__ wqT,
    ushortT* __restrict__ wpack)
{
  int idx = blockIdx.x * 256 + threadIdx.x;
  if (idx < 12288) {
    int j = idx >> 6, f = idx & 63;
    wihT[f * 192 + j] = w_ih[idx];
  } else if (idx < 24576) {
    int i = idx - 12288; int j = i >> 6, f = i & 63;
    whhT[f * 192 + j] = w_hh[i];
  } else if (idx < 32768) {
    int i = idx - 24576; int j = i >> 6, f = i & 63;
    w1T[f * 128 + j] = w1[i];
  } else if (idx < 40960) {
    int i = idx - 32768; int d = i >> 7, j = i & 127;
    w2T[j * 64 + d] = w2[i];
  } else if (idx < 45056) {
    int i = idx - 40960; int e = i >> 6, d = i & 63;
    wqT[d * 64 + e] = Wq[i];
  } else if (idx < 53248) {
    int i = idx - 45056;                 // 0..8191
    int j = i & 7, l = (i >> 3) & 63, t2 = i >> 9;
    int ct = t2 >> 1, kb = t2 & 1;
    int kf = kb * 32 + ((l >> 4) << 3) + j;
    int col = (ct << 4) | (l & 15);
    float val = (col < 64) ? Wk[col * 64 + kf] : Wv[(col - 64) * 64 + kf];
    wpack[i] = f2bf(val);
  }
}

// ---------------------------------------------------------------------------
// K1: fused LayerNorm + K/V projection via bf16 MFMA, fragment-order output.
// Stage 1: one-pass LN (sum + sumsq, interleaved shuffles, depth 4).
__global__ __launch_bounds__(256) void k_ln_project(
    const float* __restrict__ inp, const ushortT* __restrict__ wpack,
    const float* __restrict__ g, const float* __restrict__ bbv,
    ushortT* __restrict__ ktF, ushortT* __restrict__ vF)
{
  __shared__ __align__(16) ushortT xnF[4096];   // [frag8][lane64][j8]
  __shared__ __align__(16) ushortT kS[4096];    // k frags staging
  const int tid = threadIdx.x;
  const int lane = tid & 63;
  const int wave = tid >> 6;
  const int l15 = lane & 15, q = lane >> 4;
  const int tile = blockIdx.x;
  const int b = tile >> 6;
  const int c = tile & 63;
  const int n0 = c << 6;
  const float* rowbase = inp + (((long)b * NN + n0) << 6);
  const float4 g4 = *(const float4*)&g[l15 << 2];
  const float4 b4 = *(const float4*)&bbv[l15 << 2];

  // stage 1: LN, 4 rows per pass (row = wave*16 + i*4 + q, lane holds 4 cols)
#pragma unroll
  for (int i = 0; i < 4; ++i) {
    const int row = (wave << 4) + (i << 2) + q;
    float4 x = *(const float4*)&rowbase[(row << 6) + (l15 << 2)];
    float s = x.x + x.y + x.z + x.w;
    float s2 = fmaf(x.x, x.x, fmaf(x.y, x.y, fmaf(x.z, x.z, x.w * x.w)));
    s += __shfl_xor(s, 1);  s2 += __shfl_xor(s2, 1);
    s += __shfl_xor(s, 2);  s2 += __shfl_xor(s2, 2);
    s += __shfl_xor(s, 4);  s2 += __shfl_xor(s2, 4);
    s += __shfl_xor(s, 8);  s2 += __shfl_xor(s2, 8);
    const float mu = s * (1.f / 64.f);
    const float var = fmaf(-mu, mu, s2 * (1.f / 64.f));
    const float rs = rsqrtf(var + LN_EPS);
    us4 p = {f2bf((x.x - mu) * rs * g4.x + b4.x), f2bf((x.y - mu) * rs * g4.y + b4.y),
             f2bf((x.z - mu) * rs * g4.z + b4.z), f2bf((x.w - mu) * rs * g4.w + b4.w)};
    // fragment coords: n=row, d=l15*4..+3 -> frag=wave*2+(l15>>3),
    // lane'=((l15&7)>>1)*16+(row&15), j0=(l15&1)*4
    *(us4*)&xnF[((((wave << 1) + (l15 >> 3)) << 6) + (((l15 & 7) >> 1) << 4)
                 + (row & 15)) * 8 + ((l15 & 1) << 2)] = p;
  }

  // B frags (no LDS dep)
  short8 bfrag[2][2];
#pragma unroll
  for (int nt = 0; nt < 2; ++nt)
#pragma unroll
    for (int kb = 0; kb < 2; ++kb)
      bfrag[nt][kb] = *(const short8*)&wpack[((((2 * wave + nt) << 1) | kb) * 64 + lane) << 3];

  __syncthreads();

  f32x4 acc[4][2];
#pragma unroll
  for (int mt = 0; mt < 4; ++mt)
#pragma unroll
    for (int nt = 0; nt < 2; ++nt) acc[mt][nt] = (f32x4){0.f, 0.f, 0.f, 0.f};

#pragma unroll
  for (int mt = 0; mt < 4; ++mt) {
    short8 a0 = *(const short8*)&xnF[((mt * 2 + 0) * 64 + lane) << 3];
    short8 a1 = *(const short8*)&xnF[((mt * 2 + 1) * 64 + lane) << 3];
#pragma unroll
    for (int nt = 0; nt < 2; ++nt) {
      acc[mt][nt] = __builtin_amdgcn_mfma_f32_16x16x32_bf16(a0, bfrag[nt][0], acc[mt][nt], 0, 0, 0);
      acc[mt][nt] = __builtin_amdgcn_mfma_f32_16x16x32_bf16(a1, bfrag[nt][1], acc[mt][nt], 0, 0, 0);
    }
  }

  // epilogue. C: token n = mt*16 + q*4 + r, out-col = (2*wave+nt)*16 + l15
  if (wave < 2) {
#pragma unroll
    for (int mt = 0; mt < 4; ++mt)
#pragma unroll
      for (int nt = 0; nt < 2; ++nt) {
        const int base = (((mt * 2 + wave) << 6) + ((2 * nt + (l15 >> 3)) << 4) + (q << 2));
#pragma unroll
        for (int r = 0; r < 4; ++r)
          kS[((base + r) << 3) + (l15 & 7)] = f2bf(acc[mt][nt][r]);
      }
  } else {
    ushortT* vbase = vF + ((long)(b * 64 + c) << 12);
#pragma unroll
    for (int mt = 0; mt < 4; ++mt)
#pragma unroll
      for (int nt = 0; nt < 2; ++nt) {
        const int ntg = 2 * (wave - 2) + nt;
        us4 p = {f2bf(acc[mt][nt][0]), f2bf(acc[mt][nt][1]),
                 f2bf(acc[mt][nt][2]), f2bf(acc[mt][nt][3])};
        *(us4*)&vbase[(((((ntg << 1) + (mt >> 1)) << 6)
                        + (((mt & 1) * 2 + (q >> 1)) << 4) + l15) << 3)
                      + ((q & 1) << 2)] = p;
      }
  }
  __syncthreads();

  ushortT* kdst = ktF + ((long)(b * 64 + c) << 12);
  short8 v0 = *(const short8*)&kS[tid << 4];
  short8 v1 = *(const short8*)&kS[(tid << 4) + 8];
  *(short8*)&kdst[tid << 4] = v0;
  *(short8*)&kdst[(tid << 4) + 8] = v1;
}

// ---------------------------------------------------------------------------
// K2: slots init + LN + q0 as bf16 B-frag; zero acc/colsum/cnt.
__global__ __launch_bounds__(256) void k_init(
    const float* __restrict__ noise, const float* __restrict__ smu,
    const float* __restrict__ slsig, const float* __restrict__ wqT,
    const float* __restrict__ g_sl, const float* __restrict__ b_sl,
    float* __restrict__ slots, ushortT* __restrict__ qF,
    float* __restrict__ acc, float* __restrict__ colsum, int* __restrict__ cnt)
{
  __shared__ float S[4][64];
  const int tid = threadIdx.x, lane = tid & 63, wave = tid >> 6;
  const int row = blockIdx.x * 4 + wave;   // 0..511
  const int b = row >> 3, ks = row & 7;

  if (blockIdx.x == 0 && tid < 64) cnt[tid] = 0;

  float s0 = fmaf(expf(slsig[lane]), noise[row * 64 + lane], smu[lane]);
  slots[row * 64 + lane] = s0;
  acc[row * 64 + lane] = 0.f;
  if (lane == 0) colsum[row] = 0.f;

  float mu = wredsum(s0) * (1.f / 64.f);
  float dx = s0 - mu;
  float var = wredsum(dx * dx) * (1.f / 64.f);
  float sn = dx * rsqrtf(var + LN_EPS) * g_sl[lane] + b_sl[lane];
  S[wave][lane] = sn;
  __syncthreads();
  float qe = 0.f;
#pragma unroll 16
  for (int d = 0; d < 64; ++d) qe = fmaf(S[wave][d], wqT[d * 64 + lane], qe);
  const int kb = lane >> 5, lrow = (lane & 31) >> 3, j = lane & 7;
  qF[((((b * 2 + kb) << 6) + (lrow << 4) + ks) << 3) + j] = f2bf(qe * 0.125f);
  qF[((((b * 2 + kb) << 6) + (lrow << 4) + 8 + ks) << 3) + j] = 0;
}

// ---------------------------------------------------------------------------
// K3: fused attention + (last block per batch) slot update.
// attn: all-MFMA, no-max softmax. 16 blocks per batch; the 16th arriver
// consumes acc/colsum via atomicExch (which also re-zeros them) and runs
// GRU -> LN -> MLP -> residual -> next-iter q for the batch's 8 slots.
// grid 1024 x 256.
__global__ __launch_bounds__(256) void k_attn_fused(
    const ushortT* __restrict__ ktF, const ushortT* __restrict__ vF,
    ushortT* __restrict__ qF,
    float* __restrict__ acc, float* __restrict__ colsum, int* __restrict__ cnt,
    float* __restrict__ slots,
    const float* __restrict__ wihT, const float* __restrict__ whhT,
    const float* __restrict__ w1T, const float* __restrict__ w2T,
    const float* __restrict__ wqT,
    const float* __restrict__ b_ih, const float* __restrict__ b_hh,
    const float* __restrict__ mb1, const float* __restrict__ mb2,
    const float* __restrict__ g_ml, const float* __restrict__ b_ml,
    const float* __restrict__ g_sl, const float* __restrict__ b_sl,
    float* __restrict__ dout)
{
  __shared__ __align__(16) ushortT attnF[4][1024];  // per-wave P A-frags
  __shared__ float redLds[4][512];                  // accLds / update scratch
  __shared__ float colLds[4][8];
  __shared__ int flagS;
  const int tid = threadIdx.x;
  const int lane = tid & 63;
  const int wave = tid >> 6;
  const int l15 = lane & 15, q = lane >> 4;
  const int b = blockIdx.x >> 4;
  const int chunk = ((blockIdx.x & 15) << 2) | wave;  // 0..63

  const ushortT* kbF = ktF + ((long)(b * 64 + chunk) << 12);
  const ushortT* vbF = vF + ((long)(b * 64 + chunk) << 12);

  short8 kA[4][2];
#pragma unroll
  for (int mt = 0; mt < 4; ++mt)
#pragma unroll
    for (int kb = 0; kb < 2; ++kb)
      kA[mt][kb] = *(const short8*)&kbF[((mt * 2 + kb) * 64 + lane) << 3];
  short8 qB[2];
#pragma unroll
  for (int kb = 0; kb < 2; ++kb)
    qB[kb] = *(const short8*)&qF[(((b * 2 + kb) << 6) + lane) << 3];

  f32x4 accL[4];
#pragma unroll
  for (int mt = 0; mt < 4; ++mt) {
    accL[mt] = (f32x4){0.f, 0.f, 0.f, 0.f};
    accL[mt] = __builtin_amdgcn_mfma_f32_16x16x32_bf16(kA[mt][0], qB[0], accL[mt], 0, 0, 0);
    accL[mt] = __builtin_amdgcn_mfma_f32_16x16x32_bf16(kA[mt][1], qB[1], accL[mt], 0, 0, 0);
  }

  short8 vB[4][2];
#pragma unroll
  for (int nt = 0; nt < 4; ++nt)
#pragma unroll
    for (int ks = 0; ks < 2; ++ks)
      vB[nt][ks] = *(const short8*)&vbF[((nt * 2 + ks) * 64 + lane) << 3];

  // softmax over slots (no max-sub: |logit| bounded ~2 by weight scales;
  // cols 8..15 give exp(0)=1 -> benign). lane holds [n=chunk*64+mt*16+q*4+r][slot l15]
  float csum = 0.f;
#pragma unroll
  for (int mt = 0; mt < 4; ++mt) {
    float av[4];
#pragma unroll
    for (int r = 0; r < 4; ++r) {
      float ev = __expf(accL[mt][r]);
      float sv = ev;
      sv += __shfl_xor(sv, 1); sv += __shfl_xor(sv, 2); sv += __shfl_xor(sv, 4);
      float a = ev * (1.f / sv) + EPS;
      av[r] = a;
      csum += a;
    }
    us4 p = {f2bf(av[0]), f2bf(av[1]), f2bf(av[2]), f2bf(av[3])};
    *(us4*)&attnF[wave][((((mt >> 1) << 6) + (((mt & 1) * 2 + (q >> 1)) << 4)
                          + l15) << 3) + ((q & 1) << 2)] = p;
  }
  csum += __shfl_xor(csum, 16);
  csum += __shfl_xor(csum, 32);

  short8 pA0 = *(const short8*)&attnF[wave][(0 * 64 + lane) << 3];
  short8 pA1 = *(const short8*)&attnF[wave][(1 * 64 + lane) << 3];

  f32x4 accP[4];
#pragma unroll
  for (int nt = 0; nt < 4; ++nt) {
    accP[nt] = (f32x4){0.f, 0.f, 0.f, 0.f};
    accP[nt] = __builtin_amdgcn_mfma_f32_16x16x32_bf16(pA0, vB[nt][0], accP[nt], 0, 0, 0);
    accP[nt] = __builtin_amdgcn_mfma_f32_16x16x32_bf16(pA1, vB[nt][1], accP[nt], 0, 0, 0);
  }

  float (*accLds)[8][64] = (float (*)[8][64])redLds;
  if (q < 2) {
#pragma unroll
    for (int nt = 0; nt < 4; ++nt)
#pragma unroll
      for (int r = 0; r < 4; ++r)
        accLds[wave][q * 4 + r][nt * 16 + l15] = accP[nt][r];
  }
  if (q == 0 && l15 < 8) colLds[wave][l15] = csum;
  __syncthreads();

#pragma unroll
  for (int r = 0; r < 2; ++r) {
    const int o = tid + r * 256;     // 0..511 -> (k,d)
    const int kk = o >> 6, d = o & 63;
    float s = accLds[0][kk][d] + accLds[1][kk][d] + accLds[2][kk][d] + accLds[3][kk][d];
    atomicAdd(&acc[(b * 8 + kk) * 64 + d], s);
  }
  if (tid < 8) {
    float s = colLds[0][tid] + colLds[1][tid] + colLds[2][tid] + colLds[3][tid];
    atomicAdd(&colsum[b * 8 + tid], s);
  }

  // ---- arrival protocol ----
  __threadfence();
  __syncthreads();
  if (tid == 0) {
    int old = atomicAdd(&cnt[b], 1);
    flagS = (old == 15);
  }
  __syncthreads();
  if (!flagS) return;
  if (tid == 0) atomicExch(&cnt[b], 0);   // reset for next dispatch

  // ---- update phase (last block only): 8 rows, wave handles 2 ----
  float* Sw = &redLds[wave][0];
  const float bir = b_ih[lane], biz = b_ih[64 + lane], bin_ = b_ih[128 + lane];
  const float bhr = b_hh[lane], bhz = b_hh[64 + lane], bhn = b_hh[128 + lane];
  const float m1a = mb1[lane], m1b = mb1[64 + lane];
  const float m2v = mb2[lane];
  const float gml = g_ml[lane], bml = b_ml[lane];
  const float gsl = g_sl[lane], bsl = b_sl[lane];

#pragma unroll
  for (int rep = 0; rep < 2; ++rep) {
    const int ks = wave * 2 + rep;
    const int row = b * 8 + ks;

    float cs = 0.f;
    if (lane == 0) cs = atomicExch(&colsum[row], 0.f);
    cs = __shfl(cs, 0);
    const float u = atomicExch(&acc[row * 64 + lane], 0.f) / cs;
    const float h = slots[row * 64 + lane];

    Sw[lane] = u; Sw[64 + lane] = h;
    __syncthreads();

    float gir = bir, giz = biz, gin = bin_;
    float ghr = bhr, ghz = bhz, ghn = bhn;
#pragma unroll 4
    for (int f = 0; f < 64; ++f) {
      const float uf = Sw[f], hf = Sw[64 + f];
      gir = fmaf(uf, wihT[f * 192 + lane], gir);
      giz = fmaf(uf, wihT[f * 192 + 64 + lane], giz);
      gin = fmaf(uf, wihT[f * 192 + 128 + lane], gin);
      ghr = fmaf(hf, whhT[f * 192 + lane], ghr);
      ghz = fmaf(hf, whhT[f * 192 + 64 + lane], ghz);
      ghn = fmaf(hf, whhT[f * 192 + 128 + lane], ghn);
    }
    const float r = 1.f / (1.f + expf(-(gir + ghr)));
    const float z = 1.f / (1.f + expf(-(giz + ghz)));
    const float nn = tanhf(fmaf(r, ghn, gin));
    const float hnew = (1.f - z) * nn + z * h;

    float mu = wredsum(hnew) * (1.f / 64.f);
    float dx = hnew - mu;
    float var = wredsum(dx * dx) * (1.f / 64.f);
    const float ln = dx * rsqrtf(var + LN_EPS) * gml + bml;
    Sw[128 + lane] = ln;
    __syncthreads();

    float h1a = m1a, h1b = m1b;
#pragma unroll 4
    for (int f = 0; f < 64; ++f) {
      const float lf = Sw[128 + f];
      h1a = fmaf(lf, w1T[f * 128 + lane], h1a);
      h1b = fmaf(lf, w1T[f * 128 + 64 + lane], h1b);
    }
    h1a = fmaxf(h1a, 0.f); h1b = fmaxf(h1b, 0.f);
    __syncthreads();
    Sw[lane] = h1a; Sw[64 + lane] = h1b;
    __syncthreads();

    float o = m2v;
#pragma unroll 4
    for (int j = 0; j < 128; ++j) o = fmaf(Sw[j], w2T[j * 64 + lane], o);
    const float snew = hnew + o;
    slots[row * 64 + lane] = snew;
    if (dout) dout[row * 64 + lane] = snew;

    float mu2 = wredsum(snew) * (1.f / 64.f);
    float dx2 = snew - mu2;
    float v2 = wredsum(dx2 * dx2) * (1.f / 64.f);
    const float sq = dx2 * rsqrtf(v2 + LN_EPS) * gsl + bsl;
    __syncthreads();
    Sw[128 + lane] = sq;
    __syncthreads();
    float qe = 0.f;
#pragma unroll 16
    for (int d = 0; d < 64; ++d) qe = fmaf(Sw[128 + d], wqT[d * 64 + lane], qe);
    const int kb = lane >> 5, lrow = (lane & 31) >> 3, j = lane & 7;
    qF[((((b * 2 + kb) << 6) + (lrow << 4) + ks) << 3) + j] = f2bf(qe * 0.125f);
  }
}

// ---------------------------------------------------------------------------
extern "C" void kernel_launch(void* const* d_in, const int* in_sizes, int n_in,
                              void* d_out, int out_size, void* d_ws, size_t ws_size,
                              hipStream_t stream) {
  const float* inp   = (const float*)d_in[0];
  const float* noise = (const float*)d_in[1];
  const float* smu   = (const float*)d_in[2];
  const float* slsig = (const float*)d_in[3];
  const float* Wq    = (const float*)d_in[4];
  const float* Wk    = (const float*)d_in[5];
  const float* Wv    = (const float*)d_in[6];
  const float* w_ih  = (const float*)d_in[7];
  const float* w_hh  = (const float*)d_in[8];
  const float* b_ih  = (const float*)d_in[9];
  const float* b_hh  = (const float*)d_in[10];
  const float* w1    = (const float*)d_in[11];
  const float* b1    = (const float*)d_in[12];
  const float* w2    = (const float*)d_in[13];
  const float* b2    = (const float*)d_in[14];
  const float* g_in  = (const float*)d_in[15];
  const float* bi_in = (const float*)d_in[16];
  const float* g_sl  = (const float*)d_in[17];
  const float* bi_sl = (const float*)d_in[18];
  const float* g_ml  = (const float*)d_in[19];
  const float* bi_ml = (const float*)d_in[20];

  float* ws      = (float*)d_ws;
  ushortT* ktF   = (ushortT*)(ws + OFF_KT);
  ushortT* vF    = (ushortT*)(ws + OFF_V);
  ushortT* qF    = (ushortT*)(ws + OFF_QT);
  float* ac      = ws + OFF_ACC;
  float* cs      = ws + OFF_COL;
  float* sl      = ws + OFF_SLOTS;
  float* wihT    = ws + OFF_WIHT;
  float* whhT    = ws + OFF_WHHT;
  float* w1T     = ws + OFF_W1T;
  float* w2T     = ws + OFF_W2T;
  float* wqT     = ws + OFF_WQT;
  ushortT* wpk   = (ushortT*)(ws + OFF_WKV);
  int* cnt       = (int*)(ws + OFF_CNT);

  k_prep<<<208, 256, 0, stream>>>(w_ih, w_hh, w1, w2, Wq, Wk, Wv,
                                  wihT, whhT, w1T, w2T, wqT, wpk);
  k_ln_project<<<4096, 256, 0, stream>>>(inp, wpk, g_in, bi_in, ktF, vF);
  k_init<<<128, 256, 0, stream>>>(noise, smu, slsig, wqT, g_sl, bi_sl, sl, qF, ac, cs, cnt);
  for (int it = 0; it < 3; ++it) {
    k_attn_fused<<<1024, 256, 0, stream>>>(ktF, vF, qF, ac, cs, cnt, sl,
                                           wihT, whhT, w1T, w2T, wqT,
                                           b_ih, b_hh, b1, b2, g_ml, bi_ml, g_sl, bi_sl,
                                           it == 2 ? (float*)d_out : nullptr);
  }
}

// Round 6
// 325.853 us; speedup vs baseline: 1.7942x; 1.7942x over previous
//
#include <hip/hip_runtime.h>
#include <math.h>

#define NN 4096
#define LN_EPS 1e-5f
#define EPS 1e-8f

typedef unsigned short ushortT;
typedef unsigned int uintT;
typedef __attribute__((ext_vector_type(8))) short short8;
typedef __attribute__((ext_vector_type(4))) float f32x4;
typedef __attribute__((ext_vector_type(4))) unsigned short us4;

// workspace offsets (in floats)
// ktF: bf16 A-frags  [b][c=64][frag=8][lane=64][j=8] = 16.78M ushorts (32 MB)
// vF : bf16 B-frags  same shape
// qF : bf16 B-frags  [b][kb=2][lane=64][j=8] = 65536 ushorts (128 KB)
#define OFF_KT    0L
#define OFF_V     16777216L
#define OFF_QT    33554432L
#define OFF_ACC   33587200L   // acc [b][k][d] f32          32768
#define OFF_COL   33619968L   // colsum [b][k] f32          512
#define OFF_SLOTS 33620480L   // slots [b][k][d] f32        32768
#define OFF_WIHT  33653248L   // w_ih^T [64][192]           12288
#define OFF_WHHT  33665536L   // w_hh^T [64][192]           12288
#define OFF_W1T   33677824L   // mlp_w1^T [64][128]         8192
#define OFF_W2T   33686016L   // mlp_w2^T [128][64]         8192
#define OFF_WQT   33694208L   // Wq^T [64][64]              4096
#define OFF_WKV   33698304L   // wpack bf16 MFMA B-frags    8192 ushorts (4096 f)
#define OFF_CNT   33702400L   // per-batch arrival counters 64 ints

__device__ __forceinline__ float wredsum(float v) {
#pragma unroll
  for (int off = 32; off > 0; off >>= 1) v += __shfl_xor(v, off);
  return v;
}

__device__ __forceinline__ ushortT f2bf(float f) {
  uintT b = __float_as_uint(f);
  b += 0x7fff + ((b >> 16) & 1);          // RNE
  return (ushortT)(b >> 16);
}

// ---------------------------------------------------------------------------
// K0: merged weight prep + slots init. grid 208 x 256.
// All blocks: transpose/pack scatter over 53248 weight elements.
// Blocks <128: additionally slots init + LN + q0 B-frag (Wq transposed
// locally through LDS -> no dependence on the global wqT written here).
__global__ __launch_bounds__(256) void k_setup(
    const float* __restrict__ w_ih, const float* __restrict__ w_hh,
    const float* __restrict__ w1, const float* __restrict__ w2,
    const float* __restrict__ Wq,
    const float* __restrict__ Wk, const float* __restrict__ Wv,
    const float* __restrict__ noise, const float* __restrict__ smu,
    const float* __restrict__ slsig,
    const float* __restrict__ g_sl, const float* __restrict__ b_sl,
    float* __restrict__ wihT, float* __restrict__ whhT,
    float* __restrict__ w1T, float* __restrict__ w2T, float* __restrict__ wqT,
    ushortT* __restrict__ wpack,
    float* __restrict__ slots, ushortT* __restrict__ qF,
    float* __restrict__ acc, float* __restrict__ colsum, int* __restrict__ cnt)
{
  const int tid = threadIdx.x;
  int idx = blockIdx.x * 256 + tid;
  if (idx < 12288) {
    int j = idx >> 6, f = idx & 63;
    wihT[f * 192 + j] = w_ih[idx];
  } else if (idx < 24576) {
    int i = idx - 12288; int j = i >> 6, f = i & 63;
    whhT[f * 192 + j] = w_hh[i];
  } else if (idx < 32768) {
    int i = idx - 24576; int j = i >> 6, f = i & 63;
    w1T[f * 128 + j] = w1[i];
  } else if (idx < 40960) {
    int i = idx - 32768; int d = i >> 7, j = i & 127;
    w2T[j * 64 + d] = w2[i];
  } else if (idx < 45056) {
    int i = idx - 40960; int e = i >> 6, d = i & 63;
    wqT[d * 64 + e] = Wq[i];
  } else if (idx < 53248) {
    int i = idx - 45056;                 // 0..8191
    int j = i & 7, l = (i >> 3) & 63, t2 = i >> 9;
    int ct = t2 >> 1, kb = t2 & 1;
    int kf = kb * 32 + ((l >> 4) << 3) + j;
    int col = (ct << 4) | (l & 15);
    float val = (col < 64) ? Wk[col * 64 + kf] : Wv[(col - 64) * 64 + kf];
    wpack[i] = f2bf(val);
  }

  if (blockIdx.x >= 128) return;

  __shared__ float WqS[64 * 65];   // [d][e]
  __shared__ float S[4][64];
  const int lane = tid & 63, wave = tid >> 6;
  const int row = blockIdx.x * 4 + wave;   // 0..511
  const int b = row >> 3, ks = row & 7;

  if (blockIdx.x == 0 && tid < 64) cnt[tid] = 0;

  // local Wq transpose: thread holds Wq[e][d], e=idx>>6, d=idx&63
#pragma unroll
  for (int i = 0; i < 16; ++i) {
    int ii = tid + i * 256;
    int e = ii >> 6, d = ii & 63;
    WqS[d * 65 + e] = Wq[ii];
  }

  float s0 = fmaf(expf(slsig[lane]), noise[row * 64 + lane], smu[lane]);
  slots[row * 64 + lane] = s0;
  acc[row * 64 + lane] = 0.f;
  if (lane == 0) colsum[row] = 0.f;

  float mu = wredsum(s0) * (1.f / 64.f);
  float dx = s0 - mu;
  float var = wredsum(dx * dx) * (1.f / 64.f);
  float sn = dx * rsqrtf(var + LN_EPS) * g_sl[lane] + b_sl[lane];
  S[wave][lane] = sn;
  __syncthreads();
  float qe = 0.f;
#pragma unroll 16
  for (int d = 0; d < 64; ++d) qe = fmaf(S[wave][d], WqS[d * 65 + lane], qe);
  const int kb = lane >> 5, lrow = (lane & 31) >> 3, j = lane & 7;
  qF[((((b * 2 + kb) << 6) + (lrow << 4) + ks) << 3) + j] = f2bf(qe * 0.125f);
  qF[((((b * 2 + kb) << 6) + (lrow << 4) + 8 + ks) << 3) + j] = 0;
}

// ---------------------------------------------------------------------------
// K1: fused LayerNorm + K/V projection via bf16 MFMA, fragment-order output.
__global__ __launch_bounds__(256) void k_ln_project(
    const float* __restrict__ inp, const ushortT* __restrict__ wpack,
    const float* __restrict__ g, const float* __restrict__ bbv,
    ushortT* __restrict__ ktF, ushortT* __restrict__ vF)
{
  __shared__ __align__(16) ushortT xnF[4096];   // [frag8][lane64][j8]
  __shared__ __align__(16) ushortT kS[4096];    // k frags staging
  const int tid = threadIdx.x;
  const int lane = tid & 63;
  const int wave = tid >> 6;
  const int l15 = lane & 15, q = lane >> 4;
  const int tile = blockIdx.x;
  const int b = tile >> 6;
  const int c = tile & 63;
  const int n0 = c << 6;
  const float* rowbase = inp + (((long)b * NN + n0) << 6);
  const float4 g4 = *(const float4*)&g[l15 << 2];
  const float4 b4 = *(const float4*)&bbv[l15 << 2];

  // stage 1: LN, 4 rows per pass (row = wave*16 + i*4 + q, lane holds 4 cols)
#pragma unroll
  for (int i = 0; i < 4; ++i) {
    const int row = (wave << 4) + (i << 2) + q;
    float4 x = *(const float4*)&rowbase[(row << 6) + (l15 << 2)];
    float s = x.x + x.y + x.z + x.w;
    float s2 = fmaf(x.x, x.x, fmaf(x.y, x.y, fmaf(x.z, x.z, x.w * x.w)));
    s += __shfl_xor(s, 1);  s2 += __shfl_xor(s2, 1);
    s += __shfl_xor(s, 2);  s2 += __shfl_xor(s2, 2);
    s += __shfl_xor(s, 4);  s2 += __shfl_xor(s2, 4);
    s += __shfl_xor(s, 8);  s2 += __shfl_xor(s2, 8);
    const float mu = s * (1.f / 64.f);
    const float var = fmaf(-mu, mu, s2 * (1.f / 64.f));
    const float rs = rsqrtf(var + LN_EPS);
    us4 p = {f2bf((x.x - mu) * rs * g4.x + b4.x), f2bf((x.y - mu) * rs * g4.y + b4.y),
             f2bf((x.z - mu) * rs * g4.z + b4.z), f2bf((x.w - mu) * rs * g4.w + b4.w)};
    *(us4*)&xnF[((((wave << 1) + (l15 >> 3)) << 6) + (((l15 & 7) >> 1) << 4)
                 + (row & 15)) * 8 + ((l15 & 1) << 2)] = p;
  }

  short8 bfrag[2][2];
#pragma unroll
  for (int nt = 0; nt < 2; ++nt)
#pragma unroll
    for (int kb = 0; kb < 2; ++kb)
      bfrag[nt][kb] = *(const short8*)&wpack[((((2 * wave + nt) << 1) | kb) * 64 + lane) << 3];

  __syncthreads();

  f32x4 acc[4][2];
#pragma unroll
  for (int mt = 0; mt < 4; ++mt)
#pragma unroll
    for (int nt = 0; nt < 2; ++nt) acc[mt][nt] = (f32x4){0.f, 0.f, 0.f, 0.f};

#pragma unroll
  for (int mt = 0; mt < 4; ++mt) {
    short8 a0 = *(const short8*)&xnF[((mt * 2 + 0) * 64 + lane) << 3];
    short8 a1 = *(const short8*)&xnF[((mt * 2 + 1) * 64 + lane) << 3];
#pragma unroll
    for (int nt = 0; nt < 2; ++nt) {
      acc[mt][nt] = __builtin_amdgcn_mfma_f32_16x16x32_bf16(a0, bfrag[nt][0], acc[mt][nt], 0, 0, 0);
      acc[mt][nt] = __builtin_amdgcn_mfma_f32_16x16x32_bf16(a1, bfrag[nt][1], acc[mt][nt], 0, 0, 0);
    }
  }

  // epilogue. C: token n = mt*16 + q*4 + r, out-col = (2*wave+nt)*16 + l15
  if (wave < 2) {
#pragma unroll
    for (int mt = 0; mt < 4; ++mt)
#pragma unroll
      for (int nt = 0; nt < 2; ++nt) {
        const int base = (((mt * 2 + wave) << 6) + ((2 * nt + (l15 >> 3)) << 4) + (q << 2));
#pragma unroll
        for (int r = 0; r < 4; ++r)
          kS[((base + r) << 3) + (l15 & 7)] = f2bf(acc[mt][nt][r]);
      }
  } else {
    ushortT* vbase = vF + ((long)(b * 64 + c) << 12);
#pragma unroll
    for (int mt = 0; mt < 4; ++mt)
#pragma unroll
      for (int nt = 0; nt < 2; ++nt) {
        const int ntg = 2 * (wave - 2) + nt;
        us4 p = {f2bf(acc[mt][nt][0]), f2bf(acc[mt][nt][1]),
                 f2bf(acc[mt][nt][2]), f2bf(acc[mt][nt][3])};
        *(us4*)&vbase[(((((ntg << 1) + (mt >> 1)) << 6)
                        + (((mt & 1) * 2 + (q >> 1)) << 4) + l15) << 3)
                      + ((q & 1) << 2)] = p;
      }
  }
  __syncthreads();

  ushortT* kdst = ktF + ((long)(b * 64 + c) << 12);
  short8 v0 = *(const short8*)&kS[tid << 4];
  short8 v1 = *(const short8*)&kS[(tid << 4) + 8];
  *(short8*)&kdst[tid << 4] = v0;
  *(short8*)&kdst[(tid << 4) + 8] = v1;
}

// ---------------------------------------------------------------------------
// K3: fused attention + (last block per batch) slot update.
// Cross-block protocol: own atomics drained with a plain s_waitcnt (NOT a
// cache-flushing __threadfence), then cnt arrival; reader consumes acc/colsum
// via atomicExch (coherent point), which also re-zeros for the next iter.
// grid 1024 x 256.
__global__ __launch_bounds__(256) void k_attn_fused(
    const ushortT* __restrict__ ktF, const ushortT* __restrict__ vF,
    ushortT* __restrict__ qF,
    float* __restrict__ acc, float* __restrict__ colsum, int* __restrict__ cnt,
    float* __restrict__ slots,
    const float* __restrict__ wihT, const float* __restrict__ whhT,
    const float* __restrict__ w1T, const float* __restrict__ w2T,
    const float* __restrict__ wqT,
    const float* __restrict__ b_ih, const float* __restrict__ b_hh,
    const float* __restrict__ mb1, const float* __restrict__ mb2,
    const float* __restrict__ g_ml, const float* __restrict__ b_ml,
    const float* __restrict__ g_sl, const float* __restrict__ b_sl,
    float* __restrict__ dout)
{
  __shared__ __align__(16) ushortT attnF[4][1024];  // per-wave P A-frags
  __shared__ float redLds[4][512];                  // accLds / update scratch
  __shared__ float colLds[4][8];
  __shared__ int flagS;
  const int tid = threadIdx.x;
  const int lane = tid & 63;
  const int wave = tid >> 6;
  const int l15 = lane & 15, q = lane >> 4;
  const int b = blockIdx.x >> 4;
  const int chunk = ((blockIdx.x & 15) << 2) | wave;  // 0..63

  const ushortT* kbF = ktF + ((long)(b * 64 + chunk) << 12);
  const ushortT* vbF = vF + ((long)(b * 64 + chunk) << 12);

  // issue ALL fragment loads up front (18 b128s in flight)
  short8 kA[4][2];
#pragma unroll
  for (int mt = 0; mt < 4; ++mt)
#pragma unroll
    for (int kb = 0; kb < 2; ++kb)
      kA[mt][kb] = *(const short8*)&kbF[((mt * 2 + kb) * 64 + lane) << 3];
  short8 vB[4][2];
#pragma unroll
  for (int nt = 0; nt < 4; ++nt)
#pragma unroll
    for (int ks = 0; ks < 2; ++ks)
      vB[nt][ks] = *(const short8*)&vbF[((nt * 2 + ks) * 64 + lane) << 3];
  short8 qB[2];
#pragma unroll
  for (int kb = 0; kb < 2; ++kb)
    qB[kb] = *(const short8*)&qF[(((b * 2 + kb) << 6) + lane) << 3];

  f32x4 accL[4];
#pragma unroll
  for (int mt = 0; mt < 4; ++mt) {
    accL[mt] = (f32x4){0.f, 0.f, 0.f, 0.f};
    accL[mt] = __builtin_amdgcn_mfma_f32_16x16x32_bf16(kA[mt][0], qB[0], accL[mt], 0, 0, 0);
    accL[mt] = __builtin_amdgcn_mfma_f32_16x16x32_bf16(kA[mt][1], qB[1], accL[mt], 0, 0, 0);
  }

  // softmax over slots (no max-sub: |logit| bounded by small weight scales;
  // cols 8..15 give exp(0)=1 -> benign). lane holds [n=chunk*64+mt*16+q*4+r][slot l15]
  float csum = 0.f;
#pragma unroll
  for (int mt = 0; mt < 4; ++mt) {
    float av[4];
#pragma unroll
    for (int r = 0; r < 4; ++r) {
      float ev = __expf(accL[mt][r]);
      float sv = ev;
      sv += __shfl_xor(sv, 1); sv += __shfl_xor(sv, 2); sv += __shfl_xor(sv, 4);
      float a = ev * (1.f / sv) + EPS;
      av[r] = a;
      csum += a;
    }
    us4 p = {f2bf(av[0]), f2bf(av[1]), f2bf(av[2]), f2bf(av[3])};
    *(us4*)&attnF[wave][((((mt >> 1) << 6) + (((mt & 1) * 2 + (q >> 1)) << 4)
                          + l15) << 3) + ((q & 1) << 2)] = p;
  }
  csum += __shfl_xor(csum, 16);
  csum += __shfl_xor(csum, 32);

  short8 pA0 = *(const short8*)&attnF[wave][(0 * 64 + lane) << 3];
  short8 pA1 = *(const short8*)&attnF[wave][(1 * 64 + lane) << 3];

  f32x4 accP[4];
#pragma unroll
  for (int nt = 0; nt < 4; ++nt) {
    accP[nt] = (f32x4){0.f, 0.f, 0.f, 0.f};
    accP[nt] = __builtin_amdgcn_mfma_f32_16x16x32_bf16(pA0, vB[nt][0], accP[nt], 0, 0, 0);
    accP[nt] = __builtin_amdgcn_mfma_f32_16x16x32_bf16(pA1, vB[nt][1], accP[nt], 0, 0, 0);
  }

  float (*accLds)[8][64] = (float (*)[8][64])redLds;
  if (q < 2) {
#pragma unroll
    for (int nt = 0; nt < 4; ++nt)
#pragma unroll
      for (int r = 0; r < 4; ++r)
        accLds[wave][q * 4 + r][nt * 16 + l15] = accP[nt][r];
  }
  if (q == 0 && l15 < 8) colLds[wave][l15] = csum;
  __syncthreads();

#pragma unroll
  for (int r = 0; r < 2; ++r) {
    const int o = tid + r * 256;     // 0..511 -> (k,d)
    const int kk = o >> 6, d = o & 63;
    float s = accLds[0][kk][d] + accLds[1][kk][d] + accLds[2][kk][d] + accLds[3][kk][d];
    atomicAdd(&acc[(b * 8 + kk) * 64 + d], s);
  }
  if (tid < 8) {
    float s = colLds[0][tid] + colLds[1][tid] + colLds[2][tid] + colLds[3][tid];
    atomicAdd(&colsum[b * 8 + tid], s);
  }

  // ---- arrival protocol: drain OWN vmem ops (no cache flush!), then count
  asm volatile("s_waitcnt vmcnt(0) lgkmcnt(0)" ::: "memory");
  __syncthreads();
  if (tid == 0) {
    int old = atomicAdd(&cnt[b], 1);
    flagS = (old == 15);
  }
  __syncthreads();
  if (!flagS) return;
  if (tid == 0) atomicExch(&cnt[b], 0);   // reset for next dispatch

  // ---- update phase (last block only): 8 rows, wave handles 2 ----
  float* Sw = &redLds[wave][0];
  const float bir = b_ih[lane], biz = b_ih[64 + lane], bin_ = b_ih[128 + lane];
  const float bhr = b_hh[lane], bhz = b_hh[64 + lane], bhn = b_hh[128 + lane];
  const float m1a = mb1[lane], m1b = mb1[64 + lane];
  const float m2v = mb2[lane];
  const float gml = g_ml[lane], bml = b_ml[lane];
  const float gsl = g_sl[lane], bsl = b_sl[lane];

#pragma unroll
  for (int rep = 0; rep < 2; ++rep) {
    const int ks = wave * 2 + rep;
    const int row = b * 8 + ks;

    float cs = 0.f;
    if (lane == 0) cs = atomicExch(&colsum[row], 0.f);
    cs = __shfl(cs, 0);
    const float u = atomicExch(&acc[row * 64 + lane], 0.f) / cs;
    const float h = slots[row * 64 + lane];

    Sw[lane] = u; Sw[64 + lane] = h;
    __syncthreads();

    float gir = bir, giz = biz, gin = bin_;
    float ghr = bhr, ghz = bhz, ghn = bhn;
#pragma unroll 4
    for (int f = 0; f < 64; ++f) {
      const float uf = Sw[f], hf = Sw[64 + f];
      gir = fmaf(uf, wihT[f * 192 + lane], gir);
      giz = fmaf(uf, wihT[f * 192 + 64 + lane], giz);
      gin = fmaf(uf, wihT[f * 192 + 128 + lane], gin);
      ghr = fmaf(hf, whhT[f * 192 + lane], ghr);
      ghz = fmaf(hf, whhT[f * 192 + 64 + lane], ghz);
      ghn = fmaf(hf, whhT[f * 192 + 128 + lane], ghn);
    }
    const float r = 1.f / (1.f + expf(-(gir + ghr)));
    const float z = 1.f / (1.f + expf(-(giz + ghz)));
    const float nn = tanhf(fmaf(r, ghn, gin));
    const float hnew = (1.f - z) * nn + z * h;

    float mu = wredsum(hnew) * (1.f / 64.f);
    float dx = hnew - mu;
    float var = wredsum(dx * dx) * (1.f / 64.f);
    const float ln = dx * rsqrtf(var + LN_EPS) * gml + bml;
    Sw[128 + lane] = ln;
    __syncthreads();

    float h1a = m1a, h1b = m1b;
#pragma unroll 4
    for (int f = 0; f < 64; ++f) {
      const float lf = Sw[128 + f];
      h1a = fmaf(lf, w1T[f * 128 + lane], h1a);
      h1b = fmaf(lf, w1T[f * 128 + 64 + lane], h1b);
    }
    h1a = fmaxf(h1a, 0.f); h1b = fmaxf(h1b, 0.f);
    __syncthreads();
    Sw[lane] = h1a; Sw[64 + lane] = h1b;
    __syncthreads();

    float o = m2v;
#pragma unroll 4
    for (int j = 0; j < 128; ++j) o = fmaf(Sw[j], w2T[j * 64 + lane], o);
    const float snew = hnew + o;
    slots[row * 64 + lane] = snew;
    if (dout) dout[row * 64 + lane] = snew;

    float mu2 = wredsum(snew) * (1.f / 64.f);
    float dx2 = snew - mu2;
    float v2 = wredsum(dx2 * dx2) * (1.f / 64.f);
    const float sq = dx2 * rsqrtf(v2 + LN_EPS) * gsl + bsl;
    __syncthreads();
    Sw[128 + lane] = sq;
    __syncthreads();
    float qe = 0.f;
#pragma unroll 16
    for (int d = 0; d < 64; ++d) qe = fmaf(Sw[128 + d], wqT[d * 64 + lane], qe);
    const int kb = lane >> 5, lrow = (lane & 31) >> 3, j = lane & 7;
    qF[((((b * 2 + kb) << 6) + (lrow << 4) + ks) << 3) + j] = f2bf(qe * 0.125f);
  }
}

// ---------------------------------------------------------------------------
extern "C" void kernel_launch(void* const* d_in, const int* in_sizes, int n_in,
                              void* d_out, int out_size, void* d_ws, size_t ws_size,
                              hipStream_t stream) {
  const float* inp   = (const float*)d_in[0];
  const float* noise = (const float*)d_in[1];
  const float* smu   = (const float*)d_in[2];
  const float* slsig = (const float*)d_in[3];
  const float* Wq    = (const float*)d_in[4];
  const float* Wk    = (const float*)d_in[5];
  const float* Wv    = (const float*)d_in[6];
  const float* w_ih  = (const float*)d_in[7];
  const float* w_hh  = (const float*)d_in[8];
  const float* b_ih  = (const float*)d_in[9];
  const float* b_hh  = (const float*)d_in[10];
  const float* w1    = (const float*)d_in[11];
  const float* b1    = (const float*)d_in[12];
  const float* w2    = (const float*)d_in[13];
  const float* b2    = (const float*)d_in[14];
  const float* g_in  = (const float*)d_in[15];
  const float* bi_in = (const float*)d_in[16];
  const float* g_sl  = (const float*)d_in[17];
  const float* bi_sl = (const float*)d_in[18];
  const float* g_ml  = (const float*)d_in[19];
  const float* bi_ml = (const float*)d_in[20];

  float* ws      = (float*)d_ws;
  ushortT* ktF   = (ushortT*)(ws + OFF_KT);
  ushortT* vF    = (ushortT*)(ws + OFF_V);
  ushortT* qF    = (ushortT*)(ws + OFF_QT);
  float* ac      = ws + OFF_ACC;
  float* cs      = ws + OFF_COL;
  float* sl      = ws + OFF_SLOTS;
  float* wihT    = ws + OFF_WIHT;
  float* whhT    = ws + OFF_WHHT;
  float* w1T     = ws + OFF_W1T;
  float* w2T     = ws + OFF_W2T;
  float* wqT     = ws + OFF_WQT;
  ushortT* wpk   = (ushortT*)(ws + OFF_WKV);
  int* cnt       = (int*)(ws + OFF_CNT);

  k_setup<<<208, 256, 0, stream>>>(w_ih, w_hh, w1, w2, Wq, Wk, Wv,
                                   noise, smu, slsig, g_sl, bi_sl,
                                   wihT, whhT, w1T, w2T, wqT, wpk,
                                   sl, qF, ac, cs, cnt);
  k_ln_project<<<4096, 256, 0, stream>>>(inp, wpk, g_in, bi_in, ktF, vF);
  for (int it = 0; it < 3; ++it) {
    k_attn_fused<<<1024, 256, 0, stream>>>(ktF, vF, qF, ac, cs, cnt, sl,
                                           wihT, whhT, w1T, w2T, wqT,
                                           b_ih, b_hh, b1, b2, g_ml, bi_ml, g_sl, bi_sl,
                                           it == 2 ? (float*)d_out : nullptr);
  }
}

// Round 7
// 320.607 us; speedup vs baseline: 1.8236x; 1.0164x over previous
//
#include <hip/hip_runtime.h>
#include <math.h>

#define NN 4096
#define LN_EPS 1e-5f
#define EPS 1e-8f

typedef unsigned short ushortT;
typedef unsigned int uintT;
typedef __attribute__((ext_vector_type(8))) short short8;
typedef __attribute__((ext_vector_type(4))) float f32x4;
typedef __attribute__((ext_vector_type(4))) unsigned short us4;

// workspace offsets (in floats)
// ktF: bf16 A-frags  [b][c=64][frag=8][lane=64][j=8]  (16.78M ushorts)
// vF : bf16 B-frags  same shape
// qF : bf16 B-frags  [b][kb=2][lane=64][j=8]
#define OFF_KT    0L
#define OFF_V     16777216L
#define OFF_QT    33554432L
#define OFF_PART  33587200L   // part [b][blk=16][8][64] f32   524288
#define OFF_PCOL  34111488L   // pcol [b][blk=16][8] f32       8192
#define OFF_SLOTS 34119680L   // slots [b][k][d] f32           32768
#define OFF_WIHT  34152448L   // w_ih^T [64][192]              12288
#define OFF_WHHT  34164736L   // w_hh^T [64][192]              12288
#define OFF_W1T   34177024L   // mlp_w1^T [64][128]            8192
#define OFF_W2T   34185216L   // mlp_w2^T [128][64]            8192
#define OFF_WQT   34193408L   // Wq^T [64][64]                 4096
#define OFF_WKV   34197504L   // wpack bf16 MFMA B-frags       8192 ushorts
#define OFF_CNT   34201600L   // per-batch arrival counters    64 ints

__device__ __forceinline__ float wredsum(float v) {
#pragma unroll
  for (int off = 32; off > 0; off >>= 1) v += __shfl_xor(v, off);
  return v;
}

__device__ __forceinline__ ushortT f2bf(float f) {
  uintT b = __float_as_uint(f);
  b += 0x7fff + ((b >> 16) & 1);          // RNE
  return (ushortT)(b >> 16);
}

// ---------------------------------------------------------------------------
// K0: merged weight prep + slots init. grid 208 x 256.
__global__ __launch_bounds__(256) void k_setup(
    const float* __restrict__ w_ih, const float* __restrict__ w_hh,
    const float* __restrict__ w1, const float* __restrict__ w2,
    const float* __restrict__ Wq,
    const float* __restrict__ Wk, const float* __restrict__ Wv,
    const float* __restrict__ noise, const float* __restrict__ smu,
    const float* __restrict__ slsig,
    const float* __restrict__ g_sl, const float* __restrict__ b_sl,
    float* __restrict__ wihT, float* __restrict__ whhT,
    float* __restrict__ w1T, float* __restrict__ w2T, float* __restrict__ wqT,
    ushortT* __restrict__ wpack,
    float* __restrict__ slots, ushortT* __restrict__ qF,
    int* __restrict__ cnt)
{
  const int tid = threadIdx.x;
  int idx = blockIdx.x * 256 + tid;
  if (idx < 12288) {
    int j = idx >> 6, f = idx & 63;
    wihT[f * 192 + j] = w_ih[idx];
  } else if (idx < 24576) {
    int i = idx - 12288; int j = i >> 6, f = i & 63;
    whhT[f * 192 + j] = w_hh[i];
  } else if (idx < 32768) {
    int i = idx - 24576; int j = i >> 6, f = i & 63;
    w1T[f * 128 + j] = w1[i];
  } else if (idx < 40960) {
    int i = idx - 32768; int d = i >> 7, j = i & 127;
    w2T[j * 64 + d] = w2[i];
  } else if (idx < 45056) {
    int i = idx - 40960; int e = i >> 6, d = i & 63;
    wqT[d * 64 + e] = Wq[i];
  } else if (idx < 53248) {
    int i = idx - 45056;                 // 0..8191
    int j = i & 7, l = (i >> 3) & 63, t2 = i >> 9;
    int ct = t2 >> 1, kb = t2 & 1;
    int kf = kb * 32 + ((l >> 4) << 3) + j;
    int col = (ct << 4) | (l & 15);
    float val = (col < 64) ? Wk[col * 64 + kf] : Wv[(col - 64) * 64 + kf];
    wpack[i] = f2bf(val);
  }

  if (blockIdx.x >= 128) return;

  __shared__ float WqS[64 * 65];   // [d][e]
  __shared__ float S[4][64];
  const int lane = tid & 63, wave = tid >> 6;
  const int row = blockIdx.x * 4 + wave;   // 0..511
  const int b = row >> 3, ks = row & 7;

  if (blockIdx.x == 0 && tid < 64) cnt[tid] = 0;

#pragma unroll
  for (int i = 0; i < 16; ++i) {
    int ii = tid + i * 256;
    int e = ii >> 6, d = ii & 63;
    WqS[d * 65 + e] = Wq[ii];
  }

  float s0 = fmaf(expf(slsig[lane]), noise[row * 64 + lane], smu[lane]);
  slots[row * 64 + lane] = s0;

  float mu = wredsum(s0) * (1.f / 64.f);
  float dx = s0 - mu;
  float var = wredsum(dx * dx) * (1.f / 64.f);
  float sn = dx * rsqrtf(var + LN_EPS) * g_sl[lane] + b_sl[lane];
  S[wave][lane] = sn;
  __syncthreads();
  float qe = 0.f;
#pragma unroll 16
  for (int d = 0; d < 64; ++d) qe = fmaf(S[wave][d], WqS[d * 65 + lane], qe);
  const int kb = lane >> 5, lrow = (lane & 31) >> 3, j = lane & 7;
  qF[((((b * 2 + kb) << 6) + (lrow << 4) + ks) << 3) + j] = f2bf(qe * 0.125f);
  qF[((((b * 2 + kb) << 6) + (lrow << 4) + 8 + ks) << 3) + j] = 0;
}

// ---------------------------------------------------------------------------
// K1: fused LayerNorm + K/V projection via bf16 MFMA, fragment-order output.
__global__ __launch_bounds__(256, 4) void k_ln_project(
    const float* __restrict__ inp, const ushortT* __restrict__ wpack,
    const float* __restrict__ g, const float* __restrict__ bbv,
    ushortT* __restrict__ ktF, ushortT* __restrict__ vF)
{
  __shared__ __align__(16) ushortT xnF[4096];   // [frag8][lane64][j8]
  __shared__ __align__(16) ushortT kS[4096];    // k frags staging
  const int tid = threadIdx.x;
  const int lane = tid & 63;
  const int wave = tid >> 6;
  const int l15 = lane & 15, q = lane >> 4;
  const int tile = blockIdx.x;
  const int b = tile >> 6;
  const int c = tile & 63;
  const int n0 = c << 6;
  const float* rowbase = inp + (((long)b * NN + n0) << 6);
  const float4 g4 = *(const float4*)&g[l15 << 2];
  const float4 b4 = *(const float4*)&bbv[l15 << 2];

#pragma unroll
  for (int i = 0; i < 4; ++i) {
    const int row = (wave << 4) + (i << 2) + q;
    float4 x = *(const float4*)&rowbase[(row << 6) + (l15 << 2)];
    float s = x.x + x.y + x.z + x.w;
    float s2 = fmaf(x.x, x.x, fmaf(x.y, x.y, fmaf(x.z, x.z, x.w * x.w)));
    s += __shfl_xor(s, 1);  s2 += __shfl_xor(s2, 1);
    s += __shfl_xor(s, 2);  s2 += __shfl_xor(s2, 2);
    s += __shfl_xor(s, 4);  s2 += __shfl_xor(s2, 4);
    s += __shfl_xor(s, 8);  s2 += __shfl_xor(s2, 8);
    const float mu = s * (1.f / 64.f);
    const float var = fmaf(-mu, mu, s2 * (1.f / 64.f));
    const float rs = rsqrtf(var + LN_EPS);
    us4 p = {f2bf((x.x - mu) * rs * g4.x + b4.x), f2bf((x.y - mu) * rs * g4.y + b4.y),
             f2bf((x.z - mu) * rs * g4.z + b4.z), f2bf((x.w - mu) * rs * g4.w + b4.w)};
    *(us4*)&xnF[((((wave << 1) + (l15 >> 3)) << 6) + (((l15 & 7) >> 1) << 4)
                 + (row & 15)) * 8 + ((l15 & 1) << 2)] = p;
  }

  short8 bfrag[2][2];
#pragma unroll
  for (int nt = 0; nt < 2; ++nt)
#pragma unroll
    for (int kb = 0; kb < 2; ++kb)
      bfrag[nt][kb] = *(const short8*)&wpack[((((2 * wave + nt) << 1) | kb) * 64 + lane) << 3];

  __syncthreads();

  f32x4 acc[4][2];
#pragma unroll
  for (int mt = 0; mt < 4; ++mt)
#pragma unroll
    for (int nt = 0; nt < 2; ++nt) acc[mt][nt] = (f32x4){0.f, 0.f, 0.f, 0.f};

#pragma unroll
  for (int mt = 0; mt < 4; ++mt) {
    short8 a0 = *(const short8*)&xnF[((mt * 2 + 0) * 64 + lane) << 3];
    short8 a1 = *(const short8*)&xnF[((mt * 2 + 1) * 64 + lane) << 3];
#pragma unroll
    for (int nt = 0; nt < 2; ++nt) {
      acc[mt][nt] = __builtin_amdgcn_mfma_f32_16x16x32_bf16(a0, bfrag[nt][0], acc[mt][nt], 0, 0, 0);
      acc[mt][nt] = __builtin_amdgcn_mfma_f32_16x16x32_bf16(a1, bfrag[nt][1], acc[mt][nt], 0, 0, 0);
    }
  }

  if (wave < 2) {
#pragma unroll
    for (int mt = 0; mt < 4; ++mt)
#pragma unroll
      for (int nt = 0; nt < 2; ++nt) {
        const int base = (((mt * 2 + wave) << 6) + ((2 * nt + (l15 >> 3)) << 4) + (q << 2));
#pragma unroll
        for (int r = 0; r < 4; ++r)
          kS[((base + r) << 3) + (l15 & 7)] = f2bf(acc[mt][nt][r]);
      }
  } else {
    ushortT* vbase = vF + ((long)(b * 64 + c) << 12);
#pragma unroll
    for (int mt = 0; mt < 4; ++mt)
#pragma unroll
      for (int nt = 0; nt < 2; ++nt) {
        const int ntg = 2 * (wave - 2) + nt;
        us4 p = {f2bf(acc[mt][nt][0]), f2bf(acc[mt][nt][1]),
                 f2bf(acc[mt][nt][2]), f2bf(acc[mt][nt][3])};
        *(us4*)&vbase[(((((ntg << 1) + (mt >> 1)) << 6)
                        + (((mt & 1) * 2 + (q >> 1)) << 4) + l15) << 3)
                      + ((q & 1) << 2)] = p;
      }
  }
  __syncthreads();

  ushortT* kdst = ktF + ((long)(b * 64 + c) << 12);
  short8 v0 = *(const short8*)&kS[tid << 4];
  short8 v1 = *(const short8*)&kS[(tid << 4) + 8];
  *(short8*)&kdst[tid << 4] = v0;
  *(short8*)&kdst[(tid << 4) + 8] = v1;
}

// ---------------------------------------------------------------------------
// K3: fused attention + (last block per batch) slot update.
// Reduction: per-block PRIVATE partials via agent-scope coherent stores (no
// contended RMWs, no L2 flush); updater sums 16 slices with agent-scope
// loads. Arrival: own-vmem s_waitcnt + cnt atomic. grid 1024 x 256.
__global__ __launch_bounds__(256, 4) void k_attn_fused(
    const ushortT* __restrict__ ktF, const ushortT* __restrict__ vF,
    ushortT* __restrict__ qF,
    float* __restrict__ part, float* __restrict__ pcol, int* __restrict__ cnt,
    float* __restrict__ slots,
    const float* __restrict__ wihT, const float* __restrict__ whhT,
    const float* __restrict__ w1T, const float* __restrict__ w2T,
    const float* __restrict__ wqT,
    const float* __restrict__ b_ih, const float* __restrict__ b_hh,
    const float* __restrict__ mb1, const float* __restrict__ mb2,
    const float* __restrict__ g_ml, const float* __restrict__ b_ml,
    const float* __restrict__ g_sl, const float* __restrict__ b_sl,
    float* __restrict__ dout)
{
  __shared__ __align__(16) ushortT attnF[4][1024];  // P A-frags / accR reuse
  __shared__ float redLds[4][512];                  // block reduce / Sw scratch
  __shared__ float colLds[4][8];
  __shared__ int flagS;
  const int tid = threadIdx.x;
  const int lane = tid & 63;
  const int wave = tid >> 6;
  const int l15 = lane & 15, q = lane >> 4;
  const int b = blockIdx.x >> 4;
  const int i16 = blockIdx.x & 15;
  const int chunk = (i16 << 2) | wave;  // 0..63

  const ushortT* kbF = ktF + ((long)(b * 64 + chunk) << 12);
  const ushortT* vbF = vF + ((long)(b * 64 + chunk) << 12);

  // q first (logit operands complete earliest), then k, then v
  short8 qB[2];
#pragma unroll
  for (int kb = 0; kb < 2; ++kb)
    qB[kb] = *(const short8*)&qF[(((b * 2 + kb) << 6) + lane) << 3];
  short8 kA[4][2];
#pragma unroll
  for (int mt = 0; mt < 4; ++mt)
#pragma unroll
    for (int kb = 0; kb < 2; ++kb)
      kA[mt][kb] = *(const short8*)&kbF[((mt * 2 + kb) * 64 + lane) << 3];
  short8 vB[4][2];
#pragma unroll
  for (int nt = 0; nt < 4; ++nt)
#pragma unroll
    for (int ks = 0; ks < 2; ++ks)
      vB[nt][ks] = *(const short8*)&vbF[((nt * 2 + ks) * 64 + lane) << 3];

  f32x4 accL[4];
#pragma unroll
  for (int mt = 0; mt < 4; ++mt) {
    accL[mt] = (f32x4){0.f, 0.f, 0.f, 0.f};
    accL[mt] = __builtin_amdgcn_mfma_f32_16x16x32_bf16(kA[mt][0], qB[0], accL[mt], 0, 0, 0);
    accL[mt] = __builtin_amdgcn_mfma_f32_16x16x32_bf16(kA[mt][1], qB[1], accL[mt], 0, 0, 0);
  }

  // softmax over slots (no max-sub: logits bounded by small weight scales)
  float csum = 0.f;
#pragma unroll
  for (int mt = 0; mt < 4; ++mt) {
    float av[4];
#pragma unroll
    for (int r = 0; r < 4; ++r) {
      float ev = __expf(accL[mt][r]);
      float sv = ev;
      sv += __shfl_xor(sv, 1); sv += __shfl_xor(sv, 2); sv += __shfl_xor(sv, 4);
      float a = ev * (1.f / sv) + EPS;
      av[r] = a;
      csum += a;
    }
    us4 p = {f2bf(av[0]), f2bf(av[1]), f2bf(av[2]), f2bf(av[3])};
    *(us4*)&attnF[wave][((((mt >> 1) << 6) + (((mt & 1) * 2 + (q >> 1)) << 4)
                          + l15) << 3) + ((q & 1) << 2)] = p;
  }
  csum += __shfl_xor(csum, 16);
  csum += __shfl_xor(csum, 32);

  short8 pA0 = *(const short8*)&attnF[wave][(0 * 64 + lane) << 3];
  short8 pA1 = *(const short8*)&attnF[wave][(1 * 64 + lane) << 3];

  f32x4 accP[4];
#pragma unroll
  for (int nt = 0; nt < 4; ++nt) {
    accP[nt] = (f32x4){0.f, 0.f, 0.f, 0.f};
    accP[nt] = __builtin_amdgcn_mfma_f32_16x16x32_bf16(pA0, vB[nt][0], accP[nt], 0, 0, 0);
    accP[nt] = __builtin_amdgcn_mfma_f32_16x16x32_bf16(pA1, vB[nt][1], accP[nt], 0, 0, 0);
  }

  float (*accLds)[8][64] = (float (*)[8][64])redLds;
  if (q < 2) {
#pragma unroll
    for (int nt = 0; nt < 4; ++nt)
#pragma unroll
      for (int r = 0; r < 4; ++r)
        accLds[wave][q * 4 + r][nt * 16 + l15] = accP[nt][r];
  }
  if (q == 0 && l15 < 8) colLds[wave][l15] = csum;
  __syncthreads();

  // block-level reduce -> PRIVATE partial slice (coherent stores, no RMW)
  float* myPart = part + ((long)(b * 16 + i16) << 9);
#pragma unroll
  for (int r = 0; r < 2; ++r) {
    const int o = tid + r * 256;     // 0..511 -> (k,d)
    const int kk = o >> 6, d = o & 63;
    float s = accLds[0][kk][d] + accLds[1][kk][d] + accLds[2][kk][d] + accLds[3][kk][d];
    __hip_atomic_store(&myPart[o], s, __ATOMIC_RELAXED, __HIP_MEMORY_SCOPE_AGENT);
  }
  if (tid < 8) {
    float s = colLds[0][tid] + colLds[1][tid] + colLds[2][tid] + colLds[3][tid];
    __hip_atomic_store(&pcol[(b * 16 + i16) * 8 + tid], s,
                       __ATOMIC_RELAXED, __HIP_MEMORY_SCOPE_AGENT);
  }

  // ---- arrival: drain OWN stores (no cache flush), then count ----
  asm volatile("s_waitcnt vmcnt(0) lgkmcnt(0)" ::: "memory");
  __syncthreads();
  if (tid == 0) {
    int old = atomicAdd(&cnt[b], 1);
    flagS = (old == 15);
  }
  __syncthreads();
  if (!flagS) return;
  if (tid == 0) atomicExch(&cnt[b], 0);   // reset for next dispatch

  // ---- update phase (last block only) ----
  float* accR = (float*)&attnF[0][0];     // 512 floats (attnF reuse)
  float* csR  = accR + 512;               // 8 floats
  const float* partB = part + ((long)b << 13);
#pragma unroll
  for (int r = 0; r < 2; ++r) {
    const int o = tid + r * 256;
    float s = 0.f;
#pragma unroll
    for (int i = 0; i < 16; ++i)
      s += __hip_atomic_load(&partB[(i << 9) + o], __ATOMIC_RELAXED, __HIP_MEMORY_SCOPE_AGENT);
    accR[o] = s;
  }
  if (tid < 8) {
    float s = 0.f;
#pragma unroll
    for (int i = 0; i < 16; ++i)
      s += __hip_atomic_load(&pcol[(b * 16 + i) * 8 + tid], __ATOMIC_RELAXED, __HIP_MEMORY_SCOPE_AGENT);
    csR[tid] = s;
  }
  __syncthreads();

  float* Sw = &redLds[wave][0];
  const float bir = b_ih[lane], biz = b_ih[64 + lane], bin_ = b_ih[128 + lane];
  const float bhr = b_hh[lane], bhz = b_hh[64 + lane], bhn = b_hh[128 + lane];
  const float m1a = mb1[lane], m1b = mb1[64 + lane];
  const float m2v = mb2[lane];
  const float gml = g_ml[lane], bml = b_ml[lane];
  const float gsl = g_sl[lane], bsl = b_sl[lane];

#pragma unroll
  for (int rep = 0; rep < 2; ++rep) {
    const int ks = wave * 2 + rep;
    const int row = b * 8 + ks;

    const float u = accR[ks * 64 + lane] / csR[ks];
    const float h = slots[row * 64 + lane];

    Sw[lane] = u; Sw[64 + lane] = h;
    __syncthreads();

    float gir = bir, giz = biz, gin = bin_;
    float ghr = bhr, ghz = bhz, ghn = bhn;
#pragma unroll 8
    for (int f = 0; f < 64; ++f) {
      const float uf = Sw[f], hf = Sw[64 + f];
      gir = fmaf(uf, wihT[f * 192 + lane], gir);
      giz = fmaf(uf, wihT[f * 192 + 64 + lane], giz);
      gin = fmaf(uf, wihT[f * 192 + 128 + lane], gin);
      ghr = fmaf(hf, whhT[f * 192 + lane], ghr);
      ghz = fmaf(hf, whhT[f * 192 + 64 + lane], ghz);
      ghn = fmaf(hf, whhT[f * 192 + 128 + lane], ghn);
    }
    const float r = 1.f / (1.f + expf(-(gir + ghr)));
    const float z = 1.f / (1.f + expf(-(giz + ghz)));
    const float nn = tanhf(fmaf(r, ghn, gin));
    const float hnew = (1.f - z) * nn + z * h;

    float mu = wredsum(hnew) * (1.f / 64.f);
    float dx = hnew - mu;
    float var = wredsum(dx * dx) * (1.f / 64.f);
    const float ln = dx * rsqrtf(var + LN_EPS) * gml + bml;
    Sw[128 + lane] = ln;
    __syncthreads();

    float h1a = m1a, h1b = m1b;
#pragma unroll 8
    for (int f = 0; f < 64; ++f) {
      const float lf = Sw[128 + f];
      h1a = fmaf(lf, w1T[f * 128 + lane], h1a);
      h1b = fmaf(lf, w1T[f * 128 + 64 + lane], h1b);
    }
    h1a = fmaxf(h1a, 0.f); h1b = fmaxf(h1b, 0.f);
    __syncthreads();
    Sw[lane] = h1a; Sw[64 + lane] = h1b;
    __syncthreads();

    float o = m2v;
#pragma unroll 8
    for (int j = 0; j < 128; ++j) o = fmaf(Sw[j], w2T[j * 64 + lane], o);
    const float snew = hnew + o;
    slots[row * 64 + lane] = snew;
    if (dout) dout[row * 64 + lane] = snew;

    float mu2 = wredsum(snew) * (1.f / 64.f);
    float dx2 = snew - mu2;
    float v2 = wredsum(dx2 * dx2) * (1.f / 64.f);
    const float sq = dx2 * rsqrtf(v2 + LN_EPS) * gsl + bsl;
    __syncthreads();
    Sw[128 + lane] = sq;
    __syncthreads();
    float qe = 0.f;
#pragma unroll 16
    for (int d = 0; d < 64; ++d) qe = fmaf(Sw[128 + d], wqT[d * 64 + lane], qe);
    const int kb = lane >> 5, lrow = (lane & 31) >> 3, j = lane & 7;
    qF[((((b * 2 + kb) << 6) + (lrow << 4) + ks) << 3) + j] = f2bf(qe * 0.125f);
  }
}

// ---------------------------------------------------------------------------
extern "C" void kernel_launch(void* const* d_in, const int* in_sizes, int n_in,
                              void* d_out, int out_size, void* d_ws, size_t ws_size,
                              hipStream_t stream) {
  const float* inp   = (const float*)d_in[0];
  const float* noise = (const float*)d_in[1];
  const float* smu   = (const float*)d_in[2];
  const float* slsig = (const float*)d_in[3];
  const float* Wq    = (const float*)d_in[4];
  const float* Wk    = (const float*)d_in[5];
  const float* Wv    = (const float*)d_in[6];
  const float* w_ih  = (const float*)d_in[7];
  const float* w_hh  = (const float*)d_in[8];
  const float* b_ih  = (const float*)d_in[9];
  const float* b_hh  = (const float*)d_in[10];
  const float* w1    = (const float*)d_in[11];
  const float* b1    = (const float*)d_in[12];
  const float* w2    = (const float*)d_in[13];
  const float* b2    = (const float*)d_in[14];
  const float* g_in  = (const float*)d_in[15];
  const float* bi_in = (const float*)d_in[16];
  const float* g_sl  = (const float*)d_in[17];
  const float* bi_sl = (const float*)d_in[18];
  const float* g_ml  = (const float*)d_in[19];
  const float* bi_ml = (const float*)d_in[20];

  float* ws      = (float*)d_ws;
  ushortT* ktF   = (ushortT*)(ws + OFF_KT);
  ushortT* vF    = (ushortT*)(ws + OFF_V);
  ushortT* qF    = (ushortT*)(ws + OFF_QT);
  float* part    = ws + OFF_PART;
  float* pcol    = ws + OFF_PCOL;
  float* sl      = ws + OFF_SLOTS;
  float* wihT    = ws + OFF_WIHT;
  float* whhT    = ws + OFF_WHHT;
  float* w1T     = ws + OFF_W1T;
  float* w2T     = ws + OFF_W2T;
  float* wqT     = ws + OFF_WQT;
  ushortT* wpk   = (ushortT*)(ws + OFF_WKV);
  int* cnt       = (int*)(ws + OFF_CNT);

  k_setup<<<208, 256, 0, stream>>>(w_ih, w_hh, w1, w2, Wq, Wk, Wv,
                                   noise, smu, slsig, g_sl, bi_sl,
                                   wihT, whhT, w1T, w2T, wqT, wpk,
                                   sl, qF, cnt);
  k_ln_project<<<4096, 256, 0, stream>>>(inp, wpk, g_in, bi_in, ktF, vF);
  for (int it = 0; it < 3; ++it) {
    k_attn_fused<<<1024, 256, 0, stream>>>(ktF, vF, qF, part, pcol, cnt, sl,
                                           wihT, whhT, w1T, w2T, wqT,
                                           b_ih, b_hh, b1, b2, g_ml, bi_ml, g_sl, bi_sl,
                                           it == 2 ? (float*)d_out : nullptr);
  }
}

// Round 8
// 250.531 us; speedup vs baseline: 2.3337x; 1.2797x over previous
//
#include <hip/hip_runtime.h>
#include <math.h>

#define NN 4096
#define LN_EPS 1e-5f
#define EPS 1e-8f

typedef unsigned short ushortT;
typedef unsigned int uintT;
typedef __attribute__((ext_vector_type(8))) short short8;
typedef __attribute__((ext_vector_type(4))) float f32x4;
typedef __attribute__((ext_vector_type(4))) unsigned short us4;

// workspace offsets (in floats)
// ktF: bf16 A-frags  [b][c=64][frag=8][lane=64][j=8]  (16.78M ushorts)
// vF : bf16 B-frags  same shape
// qF : bf16 B-frags  [b][kb=2][lane=64][j=8]
#define OFF_KT    0L
#define OFF_V     16777216L
#define OFF_QT    33554432L
#define OFF_PART  33587200L   // part [b][blk=16][8][64] f32   524288
#define OFF_PCOL  34111488L   // pcol [b][blk=16][8] f32       8192
#define OFF_SLOTS 34119680L   // slots [b][k][d] f32           32768
#define OFF_WIHT  34152448L   // w_ih^T [64][192]              12288
#define OFF_WHHT  34164736L   // w_hh^T [64][192]              12288
#define OFF_W1T   34177024L   // mlp_w1^T [64][128]            8192
#define OFF_W2T   34185216L   // mlp_w2^T [128][64]            8192
#define OFF_WQT   34193408L   // Wq^T [64][64]                 4096
#define OFF_WKV   34197504L   // wpack bf16 MFMA B-frags       8192 ushorts
#define OFF_CNT   34201600L   // arrival counters, 1 line per batch: [64][32] ints

__device__ __forceinline__ float wredsum(float v) {
#pragma unroll
  for (int off = 32; off > 0; off >>= 1) v += __shfl_xor(v, off);
  return v;
}

__device__ __forceinline__ ushortT f2bf(float f) {
  uintT b = __float_as_uint(f);
  b += 0x7fff + ((b >> 16) & 1);          // RNE
  return (ushortT)(b >> 16);
}

// ---------------------------------------------------------------------------
// K0: merged weight prep + slots init. grid 208 x 256.
__global__ __launch_bounds__(256) void k_setup(
    const float* __restrict__ w_ih, const float* __restrict__ w_hh,
    const float* __restrict__ w1, const float* __restrict__ w2,
    const float* __restrict__ Wq,
    const float* __restrict__ Wk, const float* __restrict__ Wv,
    const float* __restrict__ noise, const float* __restrict__ smu,
    const float* __restrict__ slsig,
    const float* __restrict__ g_sl, const float* __restrict__ b_sl,
    float* __restrict__ wihT, float* __restrict__ whhT,
    float* __restrict__ w1T, float* __restrict__ w2T, float* __restrict__ wqT,
    ushortT* __restrict__ wpack,
    float* __restrict__ slots, ushortT* __restrict__ qF,
    int* __restrict__ cnt)
{
  const int tid = threadIdx.x;
  int idx = blockIdx.x * 256 + tid;
  if (idx < 12288) {
    int j = idx >> 6, f = idx & 63;
    wihT[f * 192 + j] = w_ih[idx];
  } else if (idx < 24576) {
    int i = idx - 12288; int j = i >> 6, f = i & 63;
    whhT[f * 192 + j] = w_hh[i];
  } else if (idx < 32768) {
    int i = idx - 24576; int j = i >> 6, f = i & 63;
    w1T[f * 128 + j] = w1[i];
  } else if (idx < 40960) {
    int i = idx - 32768; int d = i >> 7, j = i & 127;
    w2T[j * 64 + d] = w2[i];
  } else if (idx < 45056) {
    int i = idx - 40960; int e = i >> 6, d = i & 63;
    wqT[d * 64 + e] = Wq[i];
  } else if (idx < 53248) {
    int i = idx - 45056;                 // 0..8191
    int j = i & 7, l = (i >> 3) & 63, t2 = i >> 9;
    int ct = t2 >> 1, kb = t2 & 1;
    int kf = kb * 32 + ((l >> 4) << 3) + j;
    int col = (ct << 4) | (l & 15);
    float val = (col < 64) ? Wk[col * 64 + kf] : Wv[(col - 64) * 64 + kf];
    wpack[i] = f2bf(val);
  }

  if (blockIdx.x >= 128) {
    // blocks 128..135 zero the padded counters (64 batches x 32 ints)
    if (blockIdx.x < 136) cnt[(blockIdx.x - 128) * 256 + tid] = 0;
    return;
  }

  __shared__ float WqS[64 * 65];   // [d][e]
  __shared__ float S[4][64];
  const int lane = tid & 63, wave = tid >> 6;
  const int row = blockIdx.x * 4 + wave;   // 0..511
  const int b = row >> 3, ks = row & 7;

#pragma unroll
  for (int i = 0; i < 16; ++i) {
    int ii = tid + i * 256;
    int e = ii >> 6, d = ii & 63;
    WqS[d * 65 + e] = Wq[ii];
  }

  float s0 = fmaf(expf(slsig[lane]), noise[row * 64 + lane], smu[lane]);
  slots[row * 64 + lane] = s0;

  float mu = wredsum(s0) * (1.f / 64.f);
  float dx = s0 - mu;
  float var = wredsum(dx * dx) * (1.f / 64.f);
  float sn = dx * rsqrtf(var + LN_EPS) * g_sl[lane] + b_sl[lane];
  S[wave][lane] = sn;
  __syncthreads();
  float qe = 0.f;
#pragma unroll 16
  for (int d = 0; d < 64; ++d) qe = fmaf(S[wave][d], WqS[d * 65 + lane], qe);
  const int kb = lane >> 5, lrow = (lane & 31) >> 3, j = lane & 7;
  qF[((((b * 2 + kb) << 6) + (lrow << 4) + ks) << 3) + j] = f2bf(qe * 0.125f);
  qF[((((b * 2 + kb) << 6) + (lrow << 4) + 8 + ks) << 3) + j] = 0;
}

// ---------------------------------------------------------------------------
// K1: fused LayerNorm + K/V projection via bf16 MFMA, fragment-order output.
__global__ __launch_bounds__(256, 4) void k_ln_project(
    const float* __restrict__ inp, const ushortT* __restrict__ wpack,
    const float* __restrict__ g, const float* __restrict__ bbv,
    ushortT* __restrict__ ktF, ushortT* __restrict__ vF)
{
  __shared__ __align__(16) ushortT xnF[4096];   // [frag8][lane64][j8]
  __shared__ __align__(16) ushortT kS[4096];    // k frags staging
  const int tid = threadIdx.x;
  const int lane = tid & 63;
  const int wave = tid >> 6;
  const int l15 = lane & 15, q = lane >> 4;
  const int tile = blockIdx.x;
  const int b = tile >> 6;
  const int c = tile & 63;
  const int n0 = c << 6;
  const float* rowbase = inp + (((long)b * NN + n0) << 6);
  const float4 g4 = *(const float4*)&g[l15 << 2];
  const float4 b4 = *(const float4*)&bbv[l15 << 2];

#pragma unroll
  for (int i = 0; i < 4; ++i) {
    const int row = (wave << 4) + (i << 2) + q;
    float4 x = *(const float4*)&rowbase[(row << 6) + (l15 << 2)];
    float s = x.x + x.y + x.z + x.w;
    float s2 = fmaf(x.x, x.x, fmaf(x.y, x.y, fmaf(x.z, x.z, x.w * x.w)));
    s += __shfl_xor(s, 1);  s2 += __shfl_xor(s2, 1);
    s += __shfl_xor(s, 2);  s2 += __shfl_xor(s2, 2);
    s += __shfl_xor(s, 4);  s2 += __shfl_xor(s2, 4);
    s += __shfl_xor(s, 8);  s2 += __shfl_xor(s2, 8);
    const float mu = s * (1.f / 64.f);
    const float var = fmaf(-mu, mu, s2 * (1.f / 64.f));
    const float rs = rsqrtf(var + LN_EPS);
    us4 p = {f2bf((x.x - mu) * rs * g4.x + b4.x), f2bf((x.y - mu) * rs * g4.y + b4.y),
             f2bf((x.z - mu) * rs * g4.z + b4.z), f2bf((x.w - mu) * rs * g4.w + b4.w)};
    *(us4*)&xnF[((((wave << 1) + (l15 >> 3)) << 6) + (((l15 & 7) >> 1) << 4)
                 + (row & 15)) * 8 + ((l15 & 1) << 2)] = p;
  }

  short8 bfrag[2][2];
#pragma unroll
  for (int nt = 0; nt < 2; ++nt)
#pragma unroll
    for (int kb = 0; kb < 2; ++kb)
      bfrag[nt][kb] = *(const short8*)&wpack[((((2 * wave + nt) << 1) | kb) * 64 + lane) << 3];

  __syncthreads();

  f32x4 acc[4][2];
#pragma unroll
  for (int mt = 0; mt < 4; ++mt)
#pragma unroll
    for (int nt = 0; nt < 2; ++nt) acc[mt][nt] = (f32x4){0.f, 0.f, 0.f, 0.f};

#pragma unroll
  for (int mt = 0; mt < 4; ++mt) {
    short8 a0 = *(const short8*)&xnF[((mt * 2 + 0) * 64 + lane) << 3];
    short8 a1 = *(const short8*)&xnF[((mt * 2 + 1) * 64 + lane) << 3];
#pragma unroll
    for (int nt = 0; nt < 2; ++nt) {
      acc[mt][nt] = __builtin_amdgcn_mfma_f32_16x16x32_bf16(a0, bfrag[nt][0], acc[mt][nt], 0, 0, 0);
      acc[mt][nt] = __builtin_amdgcn_mfma_f32_16x16x32_bf16(a1, bfrag[nt][1], acc[mt][nt], 0, 0, 0);
    }
  }

  if (wave < 2) {
#pragma unroll
    for (int mt = 0; mt < 4; ++mt)
#pragma unroll
      for (int nt = 0; nt < 2; ++nt) {
        const int base = (((mt * 2 + wave) << 6) + ((2 * nt + (l15 >> 3)) << 4) + (q << 2));
#pragma unroll
        for (int r = 0; r < 4; ++r)
          kS[((base + r) << 3) + (l15 & 7)] = f2bf(acc[mt][nt][r]);
      }
  } else {
    ushortT* vbase = vF + ((long)(b * 64 + c) << 12);
#pragma unroll
    for (int mt = 0; mt < 4; ++mt)
#pragma unroll
      for (int nt = 0; nt < 2; ++nt) {
        const int ntg = 2 * (wave - 2) + nt;
        us4 p = {f2bf(acc[mt][nt][0]), f2bf(acc[mt][nt][1]),
                 f2bf(acc[mt][nt][2]), f2bf(acc[mt][nt][3])};
        *(us4*)&vbase[(((((ntg << 1) + (mt >> 1)) << 6)
                        + (((mt & 1) * 2 + (q >> 1)) << 4) + l15) << 3)
                      + ((q & 1) << 2)] = p;
      }
  }
  __syncthreads();

  ushortT* kdst = ktF + ((long)(b * 64 + c) << 12);
  short8 v0 = *(const short8*)&kS[tid << 4];
  short8 v1 = *(const short8*)&kS[(tid << 4) + 8];
  *(short8*)&kdst[tid << 4] = v0;
  *(short8*)&kdst[(tid << 4) + 8] = v1;
}

// ---------------------------------------------------------------------------
// K3: fused attention + (last block per batch) slot update.
// Arrival: padded per-batch counters (1 cacheline each) + epoch targets.
// Update tail: both slots per wave processed interleaved (weight loads
// shared), wave-private LDS, NO block barriers in the chain.
__global__ __launch_bounds__(256, 4) void k_attn_fused(
    const ushortT* __restrict__ ktF, const ushortT* __restrict__ vF,
    ushortT* __restrict__ qF,
    float* __restrict__ part, float* __restrict__ pcol, int* __restrict__ cnt,
    float* __restrict__ slots,
    const float* __restrict__ wihT, const float* __restrict__ whhT,
    const float* __restrict__ w1T, const float* __restrict__ w2T,
    const float* __restrict__ wqT,
    const float* __restrict__ b_ih, const float* __restrict__ b_hh,
    const float* __restrict__ mb1, const float* __restrict__ mb2,
    const float* __restrict__ g_ml, const float* __restrict__ b_ml,
    const float* __restrict__ g_sl, const float* __restrict__ b_sl,
    float* __restrict__ dout, int it)
{
  __shared__ __align__(16) ushortT attnF[4][1024];  // P A-frags / accR reuse
  __shared__ float redLds[4][512];                  // block reduce / Sw scratch
  __shared__ float colLds[4][8];
  __shared__ int flagS;
  const int tid = threadIdx.x;
  const int lane = tid & 63;
  const int wave = tid >> 6;
  const int l15 = lane & 15, q = lane >> 4;
  const int b = blockIdx.x >> 4;
  const int i16 = blockIdx.x & 15;
  const int chunk = (i16 << 2) | wave;  // 0..63

  const ushortT* kbF = ktF + ((long)(b * 64 + chunk) << 12);
  const ushortT* vbF = vF + ((long)(b * 64 + chunk) << 12);

  // q first, then k, then v — all independent, in flight together
  short8 qB[2];
#pragma unroll
  for (int kb = 0; kb < 2; ++kb)
    qB[kb] = *(const short8*)&qF[(((b * 2 + kb) << 6) + lane) << 3];
  short8 kA[4][2];
#pragma unroll
  for (int mt = 0; mt < 4; ++mt)
#pragma unroll
    for (int kb = 0; kb < 2; ++kb)
      kA[mt][kb] = *(const short8*)&kbF[((mt * 2 + kb) * 64 + lane) << 3];
  short8 vB[4][2];
#pragma unroll
  for (int nt = 0; nt < 4; ++nt)
#pragma unroll
    for (int ks = 0; ks < 2; ++ks)
      vB[nt][ks] = *(const short8*)&vbF[((nt * 2 + ks) * 64 + lane) << 3];

  f32x4 accL[4];
#pragma unroll
  for (int mt = 0; mt < 4; ++mt) {
    accL[mt] = (f32x4){0.f, 0.f, 0.f, 0.f};
    accL[mt] = __builtin_amdgcn_mfma_f32_16x16x32_bf16(kA[mt][0], qB[0], accL[mt], 0, 0, 0);
    accL[mt] = __builtin_amdgcn_mfma_f32_16x16x32_bf16(kA[mt][1], qB[1], accL[mt], 0, 0, 0);
  }

  // softmax over slots (no max-sub: logits bounded by small weight scales)
  float csum = 0.f;
#pragma unroll
  for (int mt = 0; mt < 4; ++mt) {
    float av[4];
#pragma unroll
    for (int r = 0; r < 4; ++r) {
      float ev = __expf(accL[mt][r]);
      float sv = ev;
      sv += __shfl_xor(sv, 1); sv += __shfl_xor(sv, 2); sv += __shfl_xor(sv, 4);
      float a = ev * (1.f / sv) + EPS;
      av[r] = a;
      csum += a;
    }
    us4 p = {f2bf(av[0]), f2bf(av[1]), f2bf(av[2]), f2bf(av[3])};
    *(us4*)&attnF[wave][((((mt >> 1) << 6) + (((mt & 1) * 2 + (q >> 1)) << 4)
                          + l15) << 3) + ((q & 1) << 2)] = p;
  }
  csum += __shfl_xor(csum, 16);
  csum += __shfl_xor(csum, 32);

  short8 pA0 = *(const short8*)&attnF[wave][(0 * 64 + lane) << 3];
  short8 pA1 = *(const short8*)&attnF[wave][(1 * 64 + lane) << 3];

  f32x4 accP[4];
#pragma unroll
  for (int nt = 0; nt < 4; ++nt) {
    accP[nt] = (f32x4){0.f, 0.f, 0.f, 0.f};
    accP[nt] = __builtin_amdgcn_mfma_f32_16x16x32_bf16(pA0, vB[nt][0], accP[nt], 0, 0, 0);
    accP[nt] = __builtin_amdgcn_mfma_f32_16x16x32_bf16(pA1, vB[nt][1], accP[nt], 0, 0, 0);
  }

  float (*accLds)[8][64] = (float (*)[8][64])redLds;
  if (q < 2) {
#pragma unroll
    for (int nt = 0; nt < 4; ++nt)
#pragma unroll
      for (int r = 0; r < 4; ++r)
        accLds[wave][q * 4 + r][nt * 16 + l15] = accP[nt][r];
  }
  if (q == 0 && l15 < 8) colLds[wave][l15] = csum;
  __syncthreads();

  // block-level reduce -> PRIVATE partial slice (coherent stores, no RMW)
  float* myPart = part + ((long)(b * 16 + i16) << 9);
#pragma unroll
  for (int r = 0; r < 2; ++r) {
    const int o = tid + r * 256;     // 0..511 -> (k,d)
    const int kk = o >> 6, d = o & 63;
    float s = accLds[0][kk][d] + accLds[1][kk][d] + accLds[2][kk][d] + accLds[3][kk][d];
    __hip_atomic_store(&myPart[o], s, __ATOMIC_RELAXED, __HIP_MEMORY_SCOPE_AGENT);
  }
  if (tid < 8) {
    float s = colLds[0][tid] + colLds[1][tid] + colLds[2][tid] + colLds[3][tid];
    __hip_atomic_store(&pcol[(b * 16 + i16) * 8 + tid], s,
                       __ATOMIC_RELAXED, __HIP_MEMORY_SCOPE_AGENT);
  }

  // ---- arrival: drain OWN stores, bump this batch's padded counter ----
  asm volatile("s_waitcnt vmcnt(0) lgkmcnt(0)" ::: "memory");
  __syncthreads();
  if (tid == 0) {
    int old = atomicAdd(&cnt[b << 5], 1);    // 1 cacheline per batch
    flagS = (old == it * 16 + 15);           // epoch target, no reset needed
  }
  __syncthreads();
  if (!flagS) return;

  // ---- update phase (last block of batch only) ----
  float* accR = (float*)&attnF[0][0];     // 512 floats (attnF reuse)
  float* csR  = accR + 512;               // 8 floats
  const float* partB = part + ((long)b << 13);
#pragma unroll
  for (int r = 0; r < 2; ++r) {
    const int o = tid + r * 256;
    float s = 0.f;
#pragma unroll
    for (int i = 0; i < 16; ++i)
      s += __hip_atomic_load(&partB[(i << 9) + o], __ATOMIC_RELAXED, __HIP_MEMORY_SCOPE_AGENT);
    accR[o] = s;
  }
  if (tid < 8) {
    float s = 0.f;
#pragma unroll
    for (int i = 0; i < 16; ++i)
      s += __hip_atomic_load(&pcol[(b * 16 + i) * 8 + tid], __ATOMIC_RELAXED, __HIP_MEMORY_SCOPE_AGENT);
    csR[tid] = s;
  }
  __syncthreads();

  // wave-private from here on: no block barriers. Wave handles slots
  // ksA=2*wave, ksB=2*wave+1 interleaved; weight loads shared across both.
  float* SwA = &redLds[wave][0];     // [0..63]=u/hid, [64..127]=h/hid, [128..191]=ln/sq
  float* SwB = &redLds[wave][256];
  const int ksA = wave * 2, ksB = ksA + 1;
  const int rowA = b * 8 + ksA, rowB = b * 8 + ksB;

  const float bir = b_ih[lane], biz = b_ih[64 + lane], bin_ = b_ih[128 + lane];
  const float bhr = b_hh[lane], bhz = b_hh[64 + lane], bhn = b_hh[128 + lane];
  const float m1a = mb1[lane], m1b = mb1[64 + lane];
  const float m2v = mb2[lane];
  const float gml = g_ml[lane], bml = b_ml[lane];
  const float gsl = g_sl[lane], bsl = b_sl[lane];

  const float u0 = accR[ksA * 64 + lane] / csR[ksA];
  const float u1 = accR[ksB * 64 + lane] / csR[ksB];
  const float h0 = slots[rowA * 64 + lane];
  const float h1 = slots[rowB * 64 + lane];
  SwA[lane] = u0; SwA[64 + lane] = h0;
  SwB[lane] = u1; SwB[64 + lane] = h1;

  float gir0 = bir, giz0 = biz, gin0 = bin_, ghr0 = bhr, ghz0 = bhz, ghn0 = bhn;
  float gir1 = bir, giz1 = biz, gin1 = bin_, ghr1 = bhr, ghz1 = bhz, ghn1 = bhn;
#pragma unroll 8
  for (int f = 0; f < 64; ++f) {
    const float wr = wihT[f * 192 + lane], wz = wihT[f * 192 + 64 + lane],
                wn = wihT[f * 192 + 128 + lane];
    const float vr = whhT[f * 192 + lane], vz = whhT[f * 192 + 64 + lane],
                vn = whhT[f * 192 + 128 + lane];
    const float uA = SwA[f], hA = SwA[64 + f];
    const float uB = SwB[f], hB = SwB[64 + f];
    gir0 = fmaf(uA, wr, gir0); giz0 = fmaf(uA, wz, giz0); gin0 = fmaf(uA, wn, gin0);
    ghr0 = fmaf(hA, vr, ghr0); ghz0 = fmaf(hA, vz, ghz0); ghn0 = fmaf(hA, vn, ghn0);
    gir1 = fmaf(uB, wr, gir1); giz1 = fmaf(uB, wz, giz1); gin1 = fmaf(uB, wn, gin1);
    ghr1 = fmaf(hB, vr, ghr1); ghz1 = fmaf(hB, vz, ghz1); ghn1 = fmaf(hB, vn, ghn1);
  }
  const float r0 = 1.f / (1.f + expf(-(gir0 + ghr0)));
  const float z0 = 1.f / (1.f + expf(-(giz0 + ghz0)));
  const float n0v = tanhf(fmaf(r0, ghn0, gin0));
  const float hnew0 = (1.f - z0) * n0v + z0 * h0;
  const float r1 = 1.f / (1.f + expf(-(gir1 + ghr1)));
  const float z1 = 1.f / (1.f + expf(-(giz1 + ghz1)));
  const float n1v = tanhf(fmaf(r1, ghn1, gin1));
  const float hnew1 = (1.f - z1) * n1v + z1 * h1;

  // LN (mlp), both slots interleaved
  float sa = hnew0, sb = hnew1;
#pragma unroll
  for (int off = 32; off > 0; off >>= 1) { sa += __shfl_xor(sa, off); sb += __shfl_xor(sb, off); }
  const float muA = sa * (1.f / 64.f), muB = sb * (1.f / 64.f);
  float dxA = hnew0 - muA, dxB = hnew1 - muB;
  float va = dxA * dxA, vb = dxB * dxB;
#pragma unroll
  for (int off = 32; off > 0; off >>= 1) { va += __shfl_xor(va, off); vb += __shfl_xor(vb, off); }
  SwA[128 + lane] = dxA * rsqrtf(va * (1.f / 64.f) + LN_EPS) * gml + bml;
  SwB[128 + lane] = dxB * rsqrtf(vb * (1.f / 64.f) + LN_EPS) * gml + bml;

  float h1a0 = m1a, h1b0 = m1b, h1a1 = m1a, h1b1 = m1b;
#pragma unroll 8
  for (int f = 0; f < 64; ++f) {
    const float wA = w1T[f * 128 + lane], wB = w1T[f * 128 + 64 + lane];
    const float lA = SwA[128 + f], lB = SwB[128 + f];
    h1a0 = fmaf(lA, wA, h1a0); h1b0 = fmaf(lA, wB, h1b0);
    h1a1 = fmaf(lB, wA, h1a1); h1b1 = fmaf(lB, wB, h1b1);
  }
  SwA[lane] = fmaxf(h1a0, 0.f); SwA[64 + lane] = fmaxf(h1b0, 0.f);
  SwB[lane] = fmaxf(h1a1, 0.f); SwB[64 + lane] = fmaxf(h1b1, 0.f);

  float o0 = m2v, o1 = m2v;
#pragma unroll 8
  for (int j = 0; j < 128; ++j) {
    const float w = w2T[j * 64 + lane];
    o0 = fmaf(SwA[j], w, o0);
    o1 = fmaf(SwB[j], w, o1);
  }
  const float snew0 = hnew0 + o0;
  const float snew1 = hnew1 + o1;
  slots[rowA * 64 + lane] = snew0;
  slots[rowB * 64 + lane] = snew1;
  if (dout) { dout[rowA * 64 + lane] = snew0; dout[rowB * 64 + lane] = snew1; }

  // next-iteration q for both slots
  float ta = snew0, tb = snew1;
#pragma unroll
  for (int off = 32; off > 0; off >>= 1) { ta += __shfl_xor(ta, off); tb += __shfl_xor(tb, off); }
  const float mu2A = ta * (1.f / 64.f), mu2B = tb * (1.f / 64.f);
  float d2A = snew0 - mu2A, d2B = snew1 - mu2B;
  float v2a = d2A * d2A, v2b = d2B * d2B;
#pragma unroll
  for (int off = 32; off > 0; off >>= 1) { v2a += __shfl_xor(v2a, off); v2b += __shfl_xor(v2b, off); }
  SwA[128 + lane] = d2A * rsqrtf(v2a * (1.f / 64.f) + LN_EPS) * gsl + bsl;
  SwB[128 + lane] = d2B * rsqrtf(v2b * (1.f / 64.f) + LN_EPS) * gsl + bsl;

  float qe0 = 0.f, qe1 = 0.f;
#pragma unroll 8
  for (int d = 0; d < 64; ++d) {
    const float w = wqT[d * 64 + lane];
    qe0 = fmaf(SwA[128 + d], w, qe0);
    qe1 = fmaf(SwB[128 + d], w, qe1);
  }
  const int kb = lane >> 5, lrow = (lane & 31) >> 3, j = lane & 7;
  qF[((((b * 2 + kb) << 6) + (lrow << 4) + ksA) << 3) + j] = f2bf(qe0 * 0.125f);
  qF[((((b * 2 + kb) << 6) + (lrow << 4) + ksB) << 3) + j] = f2bf(qe1 * 0.125f);
}

// ---------------------------------------------------------------------------
extern "C" void kernel_launch(void* const* d_in, const int* in_sizes, int n_in,
                              void* d_out, int out_size, void* d_ws, size_t ws_size,
                              hipStream_t stream) {
  const float* inp   = (const float*)d_in[0];
  const float* noise = (const float*)d_in[1];
  const float* smu   = (const float*)d_in[2];
  const float* slsig = (const float*)d_in[3];
  const float* Wq    = (const float*)d_in[4];
  const float* Wk    = (const float*)d_in[5];
  const float* Wv    = (const float*)d_in[6];
  const float* w_ih  = (const float*)d_in[7];
  const float* w_hh  = (const float*)d_in[8];
  const float* b_ih  = (const float*)d_in[9];
  const float* b_hh  = (const float*)d_in[10];
  const float* w1    = (const float*)d_in[11];
  const float* b1    = (const float*)d_in[12];
  const float* w2    = (const float*)d_in[13];
  const float* b2    = (const float*)d_in[14];
  const float* g_in  = (const float*)d_in[15];
  const float* bi_in = (const float*)d_in[16];
  const float* g_sl  = (const float*)d_in[17];
  const float* bi_sl = (const float*)d_in[18];
  const float* g_ml  = (const float*)d_in[19];
  const float* bi_ml = (const float*)d_in[20];

  float* ws      = (float*)d_ws;
  ushortT* ktF   = (ushortT*)(ws + OFF_KT);
  ushortT* vF    = (ushortT*)(ws + OFF_V);
  ushortT* qF    = (ushortT*)(ws + OFF_QT);
  float* part    = ws + OFF_PART;
  float* pcol    = ws + OFF_PCOL;
  float* sl      = ws + OFF_SLOTS;
  float* wihT    = ws + OFF_WIHT;
  float* whhT    = ws + OFF_WHHT;
  float* w1T     = ws + OFF_W1T;
  float* w2T     = ws + OFF_W2T;
  float* wqT     = ws + OFF_WQT;
  ushortT* wpk   = (ushortT*)(ws + OFF_WKV);
  int* cnt       = (int*)(ws + OFF_CNT);

  k_setup<<<208, 256, 0, stream>>>(w_ih, w_hh, w1, w2, Wq, Wk, Wv,
                                   noise, smu, slsig, g_sl, bi_sl,
                                   wihT, whhT, w1T, w2T, wqT, wpk,
                                   sl, qF, cnt);
  k_ln_project<<<4096, 256, 0, stream>>>(inp, wpk, g_in, bi_in, ktF, vF);
  for (int it = 0; it < 3; ++it) {
    k_attn_fused<<<1024, 256, 0, stream>>>(ktF, vF, qF, part, pcol, cnt, sl,
                                           wihT, whhT, w1T, w2T, wqT,
                                           b_ih, b_hh, b1, b2, g_ml, bi_ml, g_sl, bi_sl,
                                           it == 2 ? (float*)d_out : nullptr, it);
  }
}